// Round 1
// baseline (3220.630 us; speedup 1.0000x reference)
//
#include <hip/hip_runtime.h>

#define TC   50
#define BC   128
#define DXC  128
#define DYC  64
#define NMCC 100
#define NP   112
#define XFS  132
#define RBS  136
#define RCS  132
#define IVS  72
#define KTS  72

typedef float f32x4 __attribute__((ext_vector_type(4)));
typedef short s16x8 __attribute__((ext_vector_type(8)));

__device__ __forceinline__ unsigned short f2bf(float x){
  unsigned int u = __float_as_uint(x);
  u += 0x7fffu + ((u >> 16) & 1u);
  return (unsigned short)(u >> 16);
}

__device__ __forceinline__ f32x4 mfma16(s16x8 a, s16x8 b, f32x4 c){
  return __builtin_amdgcn_mfma_f32_16x16x32_bf16(a, b, c, 0, 0, 0);
}

__device__ __forceinline__ s16x8 packA8(const float* p){
  f32x4 a = *(const f32x4*)p;
  f32x4 c = *(const f32x4*)(p + 4);
  s16x8 r;
  r[0]=(short)f2bf(a[0]); r[1]=(short)f2bf(a[1]);
  r[2]=(short)f2bf(a[2]); r[3]=(short)f2bf(a[3]);
  r[4]=(short)f2bf(c[0]); r[5]=(short)f2bf(c[1]);
  r[6]=(short)f2bf(c[2]); r[7]=(short)f2bf(c[3]);
  return r;
}

// ---------------- prep: bf16 weights + taper/99 ----------------
__global__ void prep_kernel(const float* __restrict__ W1, const float* __restrict__ W2,
                            const float* __restrict__ W3, const float* __restrict__ W4,
                            unsigned short* __restrict__ w1bf, unsigned short* __restrict__ w2bf,
                            unsigned short* __restrict__ w3bf, unsigned short* __restrict__ w4bf,
                            float* __restrict__ taper){
  int tid = blockIdx.x * blockDim.x + threadIdx.x;
  int gs  = gridDim.x * blockDim.x;
  for (int i = tid; i < 128*128; i += gs) w1bf[i] = f2bf(W1[i]);
  for (int i = tid; i < 64*128;  i += gs) w2bf[i] = f2bf(W2[i]);
  for (int i = tid; i < 32*64;   i += gs) w3bf[i] = f2bf(W3[i]);
  for (int i = tid; i < 128*32;  i += gs) w4bf[i] = f2bf(W4[i]);
  for (int i = tid; i < 64*128;  i += gs){
    int o = i >> 7, e = i & 127;
    int dd = o - e; if (dd < 0) dd = -dd;
    if (128 - dd < dd) dd = 128 - dd;
    double z = (double)dd / 5.0;
    double g = 0.0;
    if (z < 1.0){
      g = 1.0 - (5.0/3.0)*z*z + (5.0/8.0)*z*z*z + 0.5*z*z*z*z - 0.25*z*z*z*z*z;
    } else if (z < 2.0){
      g = 4.0 - 5.0*z + (5.0/3.0)*z*z + (5.0/8.0)*z*z*z - 0.5*z*z*z*z
          + (1.0/12.0)*z*z*z*z*z - 2.0/(3.0*z);
    }
    taper[i] = (float)(g / 99.0);   // fold 1/(NMC-1)
  }
}

// ---------------- gin: obs @ Wih^T + bih for all (t,b) ----------------
__global__ __launch_bounds__(256) void gin_kernel(const float* __restrict__ obs,
                          const float* __restrict__ Wih, const float* __restrict__ bih,
                          float* __restrict__ gin){
  __shared__ float xrow[64];
  int blk = blockIdx.x;
  int t = blk / BC, b = blk % BC;
  int tid = threadIdx.x;
  if (tid < 64) xrow[tid] = obs[(b*TC + t)*DYC + tid];
  __syncthreads();
  float s = bih[tid];
  #pragma unroll
  for (int k = 0; k < 64; k += 4){
    f32x4 wv = *(const f32x4*)&Wih[tid*64 + k];
    s += wv[0]*xrow[k] + wv[1]*xrow[k+1] + wv[2]*xrow[k+2] + wv[3]*xrow[k+3];
  }
  gin[blk*256 + tid] = s;
}

// ---------------- lstm: recurrent part + q heads + kl ----------------
__global__ __launch_bounds__(256,1) void lstm_kernel(const float* __restrict__ gin,
     const float* __restrict__ Whh,
     const float* __restrict__ Wm, const float* __restrict__ bm,
     const float* __restrict__ Wv, const float* __restrict__ bv,
     float* __restrict__ qmean, float* __restrict__ qstd, float* __restrict__ klp){
  __shared__ float h[64], cc[64], graw[256], red[128];
  int b = blockIdx.x, tid = threadIdx.x;
  float w[64];                           // Whh row for this gate, register-resident
  #pragma unroll
  for (int k = 0; k < 64; k += 4){
    f32x4 v = *(const f32x4*)&Whh[tid*64 + k];
    w[k]=v[0]; w[k+1]=v[1]; w[k+2]=v[2]; w[k+3]=v[3];
  }
  if (tid < 64){ h[tid] = 0.f; cc[tid] = 0.f; }
  __syncthreads();
  for (int t = 0; t < TC; ++t){
    float g = gin[(t*BC + b)*256 + tid];
    #pragma unroll
    for (int k = 0; k < 64; k += 4){
      f32x4 hv = *(const f32x4*)&h[k];
      g += hv[0]*w[k] + hv[1]*w[k+1] + hv[2]*w[k+2] + hv[3]*w[k+3];
    }
    graw[tid] = g;
    __syncthreads();
    if (tid < 64){
      float ig = 1.f/(1.f + expf(-graw[tid]));
      float fg = 1.f/(1.f + expf(-graw[64 + tid]));
      float gg = tanhf(graw[128 + tid]);
      float og = 1.f/(1.f + expf(-graw[192 + tid]));
      float cn = fg*cc[tid] + ig*gg;
      cc[tid] = cn;
      h[tid] = og*tanhf(cn);
    }
    __syncthreads();
  }
  if (tid < 128){
    float sm_ = bm[tid], sv_ = bv[tid];
    #pragma unroll
    for (int k = 0; k < 64; k += 4){
      f32x4 wmv = *(const f32x4*)&Wm[tid*64 + k];
      f32x4 wvv = *(const f32x4*)&Wv[tid*64 + k];
      f32x4 hv  = *(const f32x4*)&h[k];
      sm_ += wmv[0]*hv[0] + wmv[1]*hv[1] + wmv[2]*hv[2] + wmv[3]*hv[3];
      sv_ += wvv[0]*hv[0] + wvv[1]*hv[1] + wvv[2]*hv[2] + wvv[3]*hv[3];
    }
    float qv = ((sv_ > 20.f) ? sv_ : log1pf(expf(sv_))) + 1e-4f;
    qmean[b*DXC + tid] = sm_;
    qstd[b*DXC + tid]  = sqrtf(qv);
    red[tid] = 0.5f*(qv + sm_*sm_ - 1.f - logf(qv));
  }
  __syncthreads();
  if (tid == 0){
    float s = 0.f;
    for (int i = 0; i < 128; ++i) s += red[i];
    klp[b] = s;
  }
}

// ---------------- EnKF megakernel: one block per batch b, loops t ----------------
__global__ __launch_bounds__(256,1) void enkf_kernel(
    const float* __restrict__ obs,
    const float* __restrict__ b1g, const float* __restrict__ b2g,
    const float* __restrict__ b3g, const float* __restrict__ b4g,
    const float* __restrict__ eps0, const float* __restrict__ epss,
    const float* __restrict__ nsyg,
    const unsigned short* __restrict__ w1bf, const unsigned short* __restrict__ w2bf,
    const unsigned short* __restrict__ w3bf, const unsigned short* __restrict__ w4bf,
    const float* __restrict__ taperg,
    const float* __restrict__ qmean, const float* __restrict__ qstd,
    float* __restrict__ out_means, float* __restrict__ llp)
{
  __shared__ float          sXf[NP*XFS];       // f32 master ensemble state [112][132]
  __shared__ unsigned short sRB[128*RBS];      // union: MLP acts bf16 / XcT bf16 [128][136]
  __shared__ float          sRC[64*RCS];       // union: HP->K f32 [64][132] / innov bf16 [112][72]
  __shared__ float          sRD[4608];         // union: S f32 [64][65] / KT bf16 [128][72]
  __shared__ float          sLb[64*12];        // band L: Lb[j][d] = L[j+1+d][j]
  __shared__ float          sRdiag[64];
  __shared__ float          sXm[DXC];
  __shared__ float          sYpv[DYC];
  __shared__ float          sRv[DYC];
  __shared__ float          sSc[8];

  const int b   = blockIdx.x;
  const int tid = threadIdx.x;
  const int lane = tid & 63;
  const int wid  = tid >> 6;
  const int l15  = lane & 15;
  const int l4   = lane >> 4;

  // ---- x0 init (rows >=100 stay zero forever) ----
  for (int idx = tid; idx < NP*DXC; idx += 256){
    int n = idx >> 7, d = idx & 127;
    float v = 0.f;
    if (n < NMCC) v = qmean[b*DXC + d] + qstd[b*DXC + d] * eps0[(n*BC + b)*DXC + d];
    sXf[n*XFS + d] = v;
  }
  __syncthreads();

  float llsum = 0.f;
  const f32x4 z4 = {0.f, 0.f, 0.f, 0.f};

  for (int t = 0; t < TC; ++t){
    float ldet_t = 0.f;

    // ================= MLP layer 1: [112,128]x[128,128] =================
    {
      f32x4 acc[7][2];
      #pragma unroll
      for (int m = 0; m < 7; ++m){ acc[m][0] = z4; acc[m][1] = z4; }
      #pragma unroll
      for (int kt = 0; kt < 4; ++kt){
        s16x8 af[7];
        #pragma unroll
        for (int m = 0; m < 7; ++m)
          af[m] = packA8(&sXf[(m*16 + l15)*XFS + kt*32 + 8*l4]);
        #pragma unroll
        for (int nt = 0; nt < 2; ++nt){
          int ncol = (wid*2 + nt)*16 + l15;
          s16x8 bf = *(const s16x8*)&w1bf[ncol*128 + kt*32 + 8*l4];
          #pragma unroll
          for (int m = 0; m < 7; ++m) acc[m][nt] = mfma16(af[m], bf, acc[m][nt]);
        }
      }
      #pragma unroll
      for (int nt = 0; nt < 2; ++nt){
        int col = (wid*2 + nt)*16 + l15;
        float bb = b1g[col];
        #pragma unroll
        for (int m = 0; m < 7; ++m)
          #pragma unroll
          for (int i = 0; i < 4; ++i){
            int row = m*16 + 4*l4 + i;
            sRB[row*RBS + col] = f2bf(fmaxf(acc[m][nt][i] + bb, 0.f));
          }
      }
    }
    __syncthreads();

    // ================= MLP layer 2: K=128 -> N=64 (in-place RB) =================
    {
      f32x4 acc2[7];
      #pragma unroll
      for (int m = 0; m < 7; ++m) acc2[m] = z4;
      int ncol = wid*16 + l15;   // 0..63
      #pragma unroll
      for (int kt = 0; kt < 4; ++kt){
        s16x8 bf = *(const s16x8*)&w2bf[ncol*128 + kt*32 + 8*l4];
        #pragma unroll
        for (int m = 0; m < 7; ++m){
          s16x8 af = *(const s16x8*)&sRB[(m*16 + l15)*RBS + kt*32 + 8*l4];
          acc2[m] = mfma16(af, bf, acc2[m]);
        }
      }
      __syncthreads();           // all RB reads done before overwrite
      float bb = b2g[ncol];
      #pragma unroll
      for (int m = 0; m < 7; ++m)
        #pragma unroll
        for (int i = 0; i < 4; ++i){
          int row = m*16 + 4*l4 + i;
          sRB[row*RBS + ncol] = f2bf(fmaxf(acc2[m][i] + bb, 0.f));
        }
    }
    __syncthreads();

    // ================= MLP layer 3: K=64 -> N=32 (waves 0,1) =================
    {
      f32x4 acc3[7];
      int ncol = wid*16 + l15;
      if (wid < 2){
        #pragma unroll
        for (int m = 0; m < 7; ++m) acc3[m] = z4;
        #pragma unroll
        for (int kt = 0; kt < 2; ++kt){
          s16x8 bf = *(const s16x8*)&w3bf[ncol*64 + kt*32 + 8*l4];
          #pragma unroll
          for (int m = 0; m < 7; ++m){
            s16x8 af = *(const s16x8*)&sRB[(m*16 + l15)*RBS + kt*32 + 8*l4];
            acc3[m] = mfma16(af, bf, acc3[m]);
          }
        }
      }
      __syncthreads();
      if (wid < 2){
        float bb = b3g[ncol];
        #pragma unroll
        for (int m = 0; m < 7; ++m)
          #pragma unroll
          for (int i = 0; i < 4; ++i){
            int row = m*16 + 4*l4 + i;
            sRB[row*RBS + ncol] = f2bf(fmaxf(acc3[m][i] + bb, 0.f));
          }
      }
    }
    __syncthreads();

    // ================= MLP layer 4: K=32 -> N=128, + process noise, -> Xf =================
    {
      f32x4 acc4[7][2];
      #pragma unroll
      for (int m = 0; m < 7; ++m){ acc4[m][0] = z4; acc4[m][1] = z4; }
      s16x8 af[7];
      #pragma unroll
      for (int m = 0; m < 7; ++m)
        af[m] = *(const s16x8*)&sRB[(m*16 + l15)*RBS + 8*l4];
      #pragma unroll
      for (int nt = 0; nt < 2; ++nt){
        int ncol = (wid*2 + nt)*16 + l15;
        s16x8 bf = *(const s16x8*)&w4bf[ncol*32 + 8*l4];
        #pragma unroll
        for (int m = 0; m < 7; ++m) acc4[m][nt] = mfma16(af[m], bf, acc4[m][nt]);
      }
      #pragma unroll
      for (int nt = 0; nt < 2; ++nt){
        int col = (wid*2 + nt)*16 + l15;
        float bb = b4g[col];
        #pragma unroll
        for (int m = 0; m < 7; ++m)
          #pragma unroll
          for (int i = 0; i < 4; ++i){
            int row = m*16 + 4*l4 + i;
            if (row < NMCC){
              float ev = epss[((t*NMCC + row)*BC + b)*DXC + col];
              sXf[row*XFS + col] = acc4[m][nt][i] + bb + 0.05f*ev;
            }
          }
      }
    }
    __syncthreads();

    // ================= ensemble mean =================
    if (tid < 128){
      float s = 0.f;
      #pragma unroll 4
      for (int n = 0; n < NMCC; ++n) s += sXf[n*XFS + tid];
      sXm[tid] = s * 0.01f;
    }
    __syncthreads();

    // ================= y, y_pert, r ; XcT pack (centered, bf16, transposed) =================
    if (tid < 64){
      float y  = obs[(b*TC + t)*DYC + tid];
      float ny = nsyg[(t*BC + b)*DYC + tid];
      sYpv[tid] = y + 0.1f*ny;
      sRv[tid]  = y - sXm[tid];
    }
    #pragma unroll
    for (int q = 0; q < 8; ++q){
      int d0 = wid*32 + q*4;
      #pragma unroll
      for (int pass = 0; pass < 2; ++pass){
        int n = pass*64 + lane;       // 0..127
        float v0, v1, v2, v3;
        if (n < NMCC){
          f32x4 xv = *(const f32x4*)&sXf[n*XFS + d0];
          v0 = xv[0] - sXm[d0+0]; v1 = xv[1] - sXm[d0+1];
          v2 = xv[2] - sXm[d0+2]; v3 = xv[3] - sXm[d0+3];
        } else { v0 = v1 = v2 = v3 = 0.f; }
        sRB[(d0+0)*RBS + n] = f2bf(v0);
        sRB[(d0+1)*RBS + n] = f2bf(v1);
        sRB[(d0+2)*RBS + n] = f2bf(v2);
        sRB[(d0+3)*RBS + n] = f2bf(v3);
      }
    }
    __syncthreads();

    // ================= HP = taper/99 * (XcT @ Xc)  [64 x 128] =================
    {
      f32x4 cacc[4][2];
      #pragma unroll
      for (int mt = 0; mt < 4; ++mt){ cacc[mt][0] = z4; cacc[mt][1] = z4; }
      #pragma unroll
      for (int kt = 0; kt < 4; ++kt){
        s16x8 caf[4];
        #pragma unroll
        for (int mt = 0; mt < 4; ++mt)
          caf[mt] = *(const s16x8*)&sRB[(mt*16 + l15)*RBS + kt*32 + 8*l4];
        #pragma unroll
        for (int nt = 0; nt < 2; ++nt){
          int e0 = (wid*2 + nt)*16 + l15;
          s16x8 cbf = *(const s16x8*)&sRB[e0*RBS + kt*32 + 8*l4];
          #pragma unroll
          for (int mt = 0; mt < 4; ++mt) cacc[mt][nt] = mfma16(caf[mt], cbf, cacc[mt][nt]);
        }
      }
      #pragma unroll
      for (int nt = 0; nt < 2; ++nt){
        int col = (wid*2 + nt)*16 + l15;
        #pragma unroll
        for (int mt = 0; mt < 4; ++mt)
          #pragma unroll
          for (int i = 0; i < 4; ++i){
            int row = mt*16 + 4*l4 + i;
            sRC[row*RCS + col] = cacc[mt][nt][i] * taperg[row*DXC + col];
          }
      }
    }
    __syncthreads();

    // ================= S = HP[:, :64] + 0.01 I ; rhs col 128 = r =================
    for (int idx = tid; idx < 4096; idx += 256){
      int o = idx >> 6, p = idx & 63;
      sRD[o*65 + p] = sRC[o*RCS + p] + ((o == p) ? 0.01f : 0.0f);
    }
    if (tid < 64) sRC[tid*RCS + 128] = sRv[tid];
    __syncthreads();

    // ================= banded Cholesky (wave 0; half-bandwidth 9) =================
    if (wid == 0){
      for (int j = 0; j < 64; ++j){
        __threadfence_block();
        float piv  = sRD[j*65 + j];
        float rd   = 1.0f / sqrtf(piv);
        float rpiv = rd * rd;
        if (lane == 0){ sRdiag[j] = rd; ldet_t += 0.5f * logf(piv); }
        if (lane < 9){
          int i = j + 1 + lane;
          sLb[j*12 + lane] = (i < 64) ? sRD[i*65 + j] * rd : 0.f;
        }
        // rank-1 band update over (di,dk) in [0,9)^2 : 81 pairs in 2 passes
        {
          int di = lane / 9, dk = lane % 9;   // lane<64 -> di<8
          int i = j + 1 + di, k = j + 1 + dk;
          if (i < 64 && k < 64){
            float sij = sRD[i*65 + j], skj = sRD[k*65 + j];
            sRD[i*65 + k] -= sij * skj * rpiv;
          }
        }
        {
          int p = 64 + lane;
          if (p < 81){
            int di = p / 9, dk = p % 9;
            int i = j + 1 + di, k = j + 1 + dk;
            if (i < 64 && k < 64){
              float sij = sRD[i*65 + j], skj = sRD[k*65 + j];
              sRD[i*65 + k] -= sij * skj * rpiv;
            }
          }
        }
      }
    }
    __syncthreads();

    // ================= band triangular solves: RC[:, c] <- S^-1 RC[:, c] =================
    {
      int c = tid;
      if (c < 129){
        // forward (right-looking, sliding 10-reg window)
        float w0 = sRC[0*RCS + c], w1 = sRC[1*RCS + c], w2 = sRC[2*RCS + c];
        float w3 = sRC[3*RCS + c], w4 = sRC[4*RCS + c], w5 = sRC[5*RCS + c];
        float w6 = sRC[6*RCS + c], w7 = sRC[7*RCS + c], w8 = sRC[8*RCS + c];
        float w9 = sRC[9*RCS + c];
        float z2l = 0.f;
        for (int j = 0; j < 64; ++j){
          float z = w0 * sRdiag[j];
          sRC[j*RCS + c] = z;
          z2l += z * z;
          const float* lb = &sLb[j*12];
          w0 = w1 - lb[0]*z; w1 = w2 - lb[1]*z; w2 = w3 - lb[2]*z;
          w3 = w4 - lb[3]*z; w4 = w5 - lb[4]*z; w5 = w6 - lb[5]*z;
          w6 = w7 - lb[6]*z; w7 = w8 - lb[7]*z; w8 = w9 - lb[8]*z;
          int jn = j + 10;
          w9 = (jn < 64) ? sRC[jn*RCS + c] : 0.f;
        }
        if (c == 128) sSc[0] = z2l;
        // backward (left-looking)
        float x1=0.f,x2=0.f,x3=0.f,x4=0.f,x5=0.f,x6=0.f,x7=0.f,x8=0.f,x9=0.f;
        for (int j = 63; j >= 0; --j){
          const float* lb = &sLb[j*12];
          float acc = sRC[j*RCS + c]
            - lb[0]*x1 - lb[1]*x2 - lb[2]*x3 - lb[3]*x4 - lb[4]*x5
            - lb[5]*x6 - lb[6]*x7 - lb[7]*x8 - lb[8]*x9;
          float xj = acc * sRdiag[j];
          sRC[j*RCS + c] = xj;
          x9=x8; x8=x7; x7=x6; x6=x5; x5=x4; x4=x3; x3=x2; x2=x1; x1=xj;
        }
      }
    }
    __syncthreads();

    // ================= KT pack (bf16, transposed) ; means out ; ll =================
    {
      unsigned short* KT = (unsigned short*)sRD;   // S dead, Lb/rdiag kept separately
      #pragma unroll
      for (int q = 0; q < 8; ++q){
        int e0 = wid*32 + q*4;
        f32x4 kv = *(const f32x4*)&sRC[lane*RCS + e0];
        KT[(e0+0)*KTS + lane] = f2bf(kv[0]);
        KT[(e0+1)*KTS + lane] = f2bf(kv[1]);
        KT[(e0+2)*KTS + lane] = f2bf(kv[2]);
        KT[(e0+3)*KTS + lane] = f2bf(kv[3]);
      }
    }
    if (tid < 128){
      float s = sXm[tid];
      #pragma unroll 4
      for (int o = 0; o < 64; ++o) s += sRv[o] * sRC[o*RCS + tid];
      out_means[(t*BC + b)*DXC + tid] = s;
    }
    if (tid == 0){
      llsum += -0.5f*sSc[0] - ldet_t - 58.812066f;   // 0.5*DY*log(2*pi) = 58.81207
    }
    __syncthreads();

    // ================= innov pack (bf16) over RC (K consumed) =================
    {
      unsigned short* IV = (unsigned short*)sRC;
      if (tid < 224){
        int n = tid >> 1, o0 = (tid & 1) * 32;
        if (n < NMCC){
          #pragma unroll
          for (int i = 0; i < 8; ++i){
            f32x4 xv = *(const f32x4*)&sXf[n*XFS + o0 + i*4];
            int base = n*IVS + o0 + i*4;
            IV[base+0] = f2bf(sYpv[o0+i*4+0] - xv[0]);
            IV[base+1] = f2bf(sYpv[o0+i*4+1] - xv[1]);
            IV[base+2] = f2bf(sYpv[o0+i*4+2] - xv[2]);
            IV[base+3] = f2bf(sYpv[o0+i*4+3] - xv[3]);
          }
        } else {
          unsigned int* p = (unsigned int*)&IV[n*IVS + o0];
          #pragma unroll
          for (int i = 0; i < 16; ++i) p[i] = 0u;
        }
      }
    }
    __syncthreads();

    // ================= update: Xf += innov @ K  =================
    {
      const unsigned short* IV = (const unsigned short*)sRC;
      const unsigned short* KT = (const unsigned short*)sRD;
      f32x4 uacc[7][2];
      #pragma unroll
      for (int m = 0; m < 7; ++m){ uacc[m][0] = z4; uacc[m][1] = z4; }
      #pragma unroll
      for (int kt = 0; kt < 2; ++kt){
        s16x8 af[7];
        #pragma unroll
        for (int m = 0; m < 7; ++m)
          af[m] = *(const s16x8*)&IV[(m*16 + l15)*IVS + kt*32 + 8*l4];
        #pragma unroll
        for (int nt = 0; nt < 2; ++nt){
          int e0 = (wid*2 + nt)*16 + l15;
          s16x8 bf = *(const s16x8*)&KT[e0*KTS + kt*32 + 8*l4];
          #pragma unroll
          for (int m = 0; m < 7; ++m) uacc[m][nt] = mfma16(af[m], bf, uacc[m][nt]);
        }
      }
      #pragma unroll
      for (int m = 0; m < 7; ++m)
        #pragma unroll
        for (int nt = 0; nt < 2; ++nt){
          int col = (wid*2 + nt)*16 + l15;
          #pragma unroll
          for (int i = 0; i < 4; ++i){
            int row = m*16 + 4*l4 + i;
            if (row < NMCC) sXf[row*XFS + col] += uacc[m][nt][i];
          }
        }
    }
    __syncthreads();
  } // t loop

  if (tid == 0) llp[b] = llsum;
}

// ---------------- final: elbo = -mean(kl) + sum_t mean_b ll ----------------
__global__ void final_kernel(const float* __restrict__ klp, const float* __restrict__ llp,
                             float* __restrict__ out){
  __shared__ float s1[128], s2[128];
  int tid = threadIdx.x;
  s1[tid] = klp[tid];
  s2[tid] = llp[tid];
  __syncthreads();
  if (tid == 0){
    float a = 0.f, c = 0.f;
    for (int i = 0; i < 128; ++i){ a += s1[i]; c += s2[i]; }
    out[0] = -a/128.f + c/128.f;
  }
}

extern "C" void kernel_launch(void* const* d_in, const int* in_sizes, int n_in,
                              void* d_out, int out_size, void* d_ws, size_t ws_size,
                              hipStream_t stream){
  (void)in_sizes; (void)n_in; (void)out_size; (void)ws_size;
  const float* obs  = (const float*)d_in[0];
  const float* W1   = (const float*)d_in[1];
  const float* b1   = (const float*)d_in[2];
  const float* W2   = (const float*)d_in[3];
  const float* b2   = (const float*)d_in[4];
  const float* W3   = (const float*)d_in[5];
  const float* b3   = (const float*)d_in[6];
  const float* W4   = (const float*)d_in[7];
  const float* b4   = (const float*)d_in[8];
  const float* Wih  = (const float*)d_in[9];
  const float* Whh  = (const float*)d_in[10];
  const float* bih  = (const float*)d_in[11];
  const float* Wm   = (const float*)d_in[12];
  const float* bm   = (const float*)d_in[13];
  const float* Wv   = (const float*)d_in[14];
  const float* bv   = (const float*)d_in[15];
  const float* eps0 = (const float*)d_in[16];
  const float* epss = (const float*)d_in[17];
  const float* nsy  = (const float*)d_in[18];

  char* ws = (char*)d_ws;
  unsigned short* w1bf = (unsigned short*)(ws + 0);
  unsigned short* w2bf = (unsigned short*)(ws + 32768);
  unsigned short* w3bf = (unsigned short*)(ws + 49152);
  unsigned short* w4bf = (unsigned short*)(ws + 53248);
  float* taper = (float*)(ws + 61440);
  float* gin   = (float*)(ws + 94208);
  float* qmean = (float*)(ws + 6647808);
  float* qstd  = (float*)(ws + 6713344);
  float* klp   = (float*)(ws + 6778880);
  float* llp   = (float*)(ws + 6779392);

  float* out = (float*)d_out;

  hipLaunchKernelGGL(prep_kernel, dim3(64), dim3(256), 0, stream,
                     W1, W2, W3, W4, w1bf, w2bf, w3bf, w4bf, taper);
  hipLaunchKernelGGL(gin_kernel, dim3(TC*BC), dim3(256), 0, stream,
                     obs, Wih, bih, gin);
  hipLaunchKernelGGL(lstm_kernel, dim3(BC), dim3(256), 0, stream,
                     gin, Whh, Wm, bm, Wv, bv, qmean, qstd, klp);
  hipLaunchKernelGGL(enkf_kernel, dim3(BC), dim3(256), 0, stream,
                     obs, b1, b2, b3, b4, eps0, epss, nsy,
                     w1bf, w2bf, w3bf, w4bf, taper, qmean, qstd, out + 1, llp);
  hipLaunchKernelGGL(final_kernel, dim3(1), dim3(128), 0, stream, klp, llp, out);
}

// Round 2
// 2494.056 us; speedup vs baseline: 1.2913x; 1.2913x over previous
//
#include <hip/hip_runtime.h>

#define TC   50
#define BC   128
#define DXC  128
#define DYC  64
#define NMCC 100
#define NP   112
#define XFS  132
#define RBS  136
#define RCS  132
#define IVS  72
#define KTS  72
#define NTHREADS 512

typedef float f32x4 __attribute__((ext_vector_type(4)));
typedef short s16x8 __attribute__((ext_vector_type(8)));

__device__ __forceinline__ unsigned short f2bf(float x){
  unsigned int u = __float_as_uint(x);
  u += 0x7fffu + ((u >> 16) & 1u);
  return (unsigned short)(u >> 16);
}

__device__ __forceinline__ f32x4 mfma16(s16x8 a, s16x8 b, f32x4 c){
  return __builtin_amdgcn_mfma_f32_16x16x32_bf16(a, b, c, 0, 0, 0);
}

__device__ __forceinline__ s16x8 packA8(const float* p){
  f32x4 a = *(const f32x4*)p;
  f32x4 c = *(const f32x4*)(p + 4);
  s16x8 r;
  r[0]=(short)f2bf(a[0]); r[1]=(short)f2bf(a[1]);
  r[2]=(short)f2bf(a[2]); r[3]=(short)f2bf(a[3]);
  r[4]=(short)f2bf(c[0]); r[5]=(short)f2bf(c[1]);
  r[6]=(short)f2bf(c[2]); r[7]=(short)f2bf(c[3]);
  return r;
}

__device__ __forceinline__ float gc_taper(int row, int col){
  int dd = row - col; if (dd < 0) dd = -dd;
  if (128 - dd < dd) dd = 128 - dd;
  double z = (double)dd / 5.0;
  double g = 0.0;
  if (z < 1.0){
    g = 1.0 - (5.0/3.0)*z*z + (5.0/8.0)*z*z*z + 0.5*z*z*z*z - 0.25*z*z*z*z*z;
  } else if (z < 2.0){
    g = 4.0 - 5.0*z + (5.0/3.0)*z*z + (5.0/8.0)*z*z*z - 0.5*z*z*z*z
        + (1.0/12.0)*z*z*z*z*z - 2.0/(3.0*z);
  }
  return (float)(g / 99.0);   // fold 1/(NMC-1)
}

// ---------------- gin: obs @ Wih^T + bih for all (t,b) ----------------
__global__ __launch_bounds__(256) void gin_kernel(const float* __restrict__ obs,
                          const float* __restrict__ Wih, const float* __restrict__ bih,
                          float* __restrict__ gin){
  __shared__ float xrow[64];
  int blk = blockIdx.x;
  int t = blk / BC, b = blk % BC;
  int tid = threadIdx.x;
  if (tid < 64) xrow[tid] = obs[(b*TC + t)*DYC + tid];
  __syncthreads();
  float s = bih[tid];
  #pragma unroll
  for (int k = 0; k < 64; k += 4){
    f32x4 wv = *(const f32x4*)&Wih[tid*64 + k];
    s += wv[0]*xrow[k] + wv[1]*xrow[k+1] + wv[2]*xrow[k+2] + wv[3]*xrow[k+3];
  }
  gin[blk*256 + tid] = s;
}

// ---------------- lstm: recurrent part + q heads + kl ----------------
__global__ __launch_bounds__(256,1) void lstm_kernel(const float* __restrict__ gin,
     const float* __restrict__ Whh,
     const float* __restrict__ Wm, const float* __restrict__ bm,
     const float* __restrict__ Wv, const float* __restrict__ bv,
     float* __restrict__ qmean, float* __restrict__ qstd, float* __restrict__ klp){
  __shared__ float h[64], cc[64], graw[256], red[128];
  int b = blockIdx.x, tid = threadIdx.x;
  float w[64];
  #pragma unroll
  for (int k = 0; k < 64; k += 4){
    f32x4 v = *(const f32x4*)&Whh[tid*64 + k];
    w[k]=v[0]; w[k+1]=v[1]; w[k+2]=v[2]; w[k+3]=v[3];
  }
  if (tid < 64){ h[tid] = 0.f; cc[tid] = 0.f; }
  __syncthreads();
  for (int t = 0; t < TC; ++t){
    float g = gin[(t*BC + b)*256 + tid];
    #pragma unroll
    for (int k = 0; k < 64; k += 4){
      f32x4 hv = *(const f32x4*)&h[k];
      g += hv[0]*w[k] + hv[1]*w[k+1] + hv[2]*w[k+2] + hv[3]*w[k+3];
    }
    graw[tid] = g;
    __syncthreads();
    if (tid < 64){
      float ig = 1.f/(1.f + expf(-graw[tid]));
      float fg = 1.f/(1.f + expf(-graw[64 + tid]));
      float gg = tanhf(graw[128 + tid]);
      float og = 1.f/(1.f + expf(-graw[192 + tid]));
      float cn = fg*cc[tid] + ig*gg;
      cc[tid] = cn;
      h[tid] = og*tanhf(cn);
    }
    __syncthreads();
  }
  if (tid < 128){
    float sm_ = bm[tid], sv_ = bv[tid];
    #pragma unroll
    for (int k = 0; k < 64; k += 4){
      f32x4 wmv = *(const f32x4*)&Wm[tid*64 + k];
      f32x4 wvv = *(const f32x4*)&Wv[tid*64 + k];
      f32x4 hv  = *(const f32x4*)&h[k];
      sm_ += wmv[0]*hv[0] + wmv[1]*hv[1] + wmv[2]*hv[2] + wmv[3]*hv[3];
      sv_ += wvv[0]*hv[0] + wvv[1]*hv[1] + wvv[2]*hv[2] + wvv[3]*hv[3];
    }
    float qv = ((sv_ > 20.f) ? sv_ : log1pf(expf(sv_))) + 1e-4f;
    qmean[b*DXC + tid] = sm_;
    qstd[b*DXC + tid]  = sqrtf(qv);
    red[tid] = 0.5f*(qv + sm_*sm_ - 1.f - logf(qv));
  }
  __syncthreads();
  if (tid == 0){
    float s = 0.f;
    for (int i = 0; i < 128; ++i) s += red[i];
    klp[b] = s;
  }
}

// ---------------- EnKF megakernel: one block (8 waves) per batch b ----------------
__global__ __launch_bounds__(NTHREADS,2) void enkf_kernel(
    const float* __restrict__ obs,
    const float* __restrict__ W1, const float* __restrict__ b1g,
    const float* __restrict__ W2, const float* __restrict__ b2g,
    const float* __restrict__ W3, const float* __restrict__ b3g,
    const float* __restrict__ W4, const float* __restrict__ b4g,
    const float* __restrict__ eps0, const float* __restrict__ epss,
    const float* __restrict__ nsyg,
    const float* __restrict__ qmean, const float* __restrict__ qstd,
    float* __restrict__ out_means, float* __restrict__ llp)
{
  __shared__ float          sXf[NP*XFS];       // f32 master ensemble [112][132]
  __shared__ unsigned short sRB[128*RBS];      // acts1 / acts3 / XcT / innov
  __shared__ float          sRC[64*RCS];       // acts2(bf16) / HP->K f32 [64][132]
  __shared__ float          sRD[4608];         // S f32 [64][65] / KT bf16 [128][72]
  __shared__ float          sLb[64*12];
  __shared__ float          sRdiag[64];
  __shared__ float          sXm[DXC];
  __shared__ float          sYpv[DYC];
  __shared__ float          sRv[DYC];
  __shared__ float          sSc[8];

  const int b    = blockIdx.x;
  const int tid  = threadIdx.x;
  const int lane = tid & 63;
  const int wid  = tid >> 6;          // 0..7
  const int l15  = lane & 15;
  const int l4   = lane >> 4;

  const int colN = wid*16 + l15;                 // L1/L4/cov/update col
  const int col2 = (wid & 3)*16 + l15;           // L2 col
  const int col3 = (wid & 1)*16 + l15;           // L3 col
  const int m02  = (wid >> 2) * 4;               // L2 m-tile base
  const int mc2  = (wid >> 2) ? 3 : 4;
  const int m03  = (wid >> 1) * 2;               // L3 m-tile base
  const int mc3  = ((wid >> 1) == 3) ? 1 : 2;

  // ---- hoisted weight fragments (t-invariant) ----
  s16x8 w1f[4], w2f[4], w3f[2], w4f;
  #pragma unroll
  for (int kt = 0; kt < 4; ++kt) w1f[kt] = packA8(&W1[colN*128 + kt*32 + 8*l4]);
  #pragma unroll
  for (int kt = 0; kt < 4; ++kt) w2f[kt] = packA8(&W2[col2*128 + kt*32 + 8*l4]);
  #pragma unroll
  for (int kt = 0; kt < 2; ++kt) w3f[kt] = packA8(&W3[col3*64 + kt*32 + 8*l4]);
  w4f = packA8(&W4[colN*32 + 8*l4]);
  const float bb1 = b1g[colN], bb2 = b2g[col2], bb3 = b3g[col3], bb4 = b4g[colN];

  // ---- hoisted taper values for cov epilogue ----
  float tv[4][4];
  #pragma unroll
  for (int mt = 0; mt < 4; ++mt)
    #pragma unroll
    for (int i = 0; i < 4; ++i)
      tv[mt][i] = gc_taper(mt*16 + 4*l4 + i, colN);

  // ---- chol pair assignment constants ----
  const int di1 = lane / 9, dk1 = lane % 9;
  const int di2 = (64 + lane) / 9, dk2 = (64 + lane) % 9;
  const bool has2 = (lane < 17);

  // ---- x0 init (rows >=100 stay zero forever) ----
  for (int idx = tid; idx < NP*DXC; idx += NTHREADS){
    int n = idx >> 7, d = idx & 127;
    float v = 0.f;
    if (n < NMCC) v = qmean[b*DXC + d] + qstd[b*DXC + d] * eps0[(n*BC + b)*DXC + d];
    sXf[n*XFS + d] = v;
  }

  // ---- prefetch eps for t=0 into registers ----
  float ev[7][4];
  #pragma unroll
  for (int m = 0; m < 7; ++m)
    #pragma unroll
    for (int i = 0; i < 4; ++i){
      int row = m*16 + 4*l4 + i;
      ev[m][i] = (row < NMCC)
        ? epss[((size_t)row*BC + b)*DXC + colN] : 0.f;
    }
  __syncthreads();

  float llsum = 0.f;
  const f32x4 z4 = {0.f, 0.f, 0.f, 0.f};

  for (int t = 0; t < TC; ++t){
    float ldet_t = 0.f;

    // issue y loads early (consumed in P5)
    float y_r = 0.f, ny_r = 0.f;
    if (tid < 64){
      y_r  = obs[(b*TC + t)*DYC + tid];
      ny_r = nsyg[(t*BC + b)*DYC + tid];
    }

    // ============ P1: MLP L1  [112,128]x[128,128] -> sRB (acts1) ============
    {
      f32x4 acc[7];
      #pragma unroll
      for (int m = 0; m < 7; ++m) acc[m] = z4;
      #pragma unroll
      for (int kt = 0; kt < 4; ++kt){
        s16x8 af[7];
        #pragma unroll
        for (int m = 0; m < 7; ++m)
          af[m] = packA8(&sXf[(m*16 + l15)*XFS + kt*32 + 8*l4]);
        #pragma unroll
        for (int m = 0; m < 7; ++m) acc[m] = mfma16(af[m], w1f[kt], acc[m]);
      }
      #pragma unroll
      for (int m = 0; m < 7; ++m)
        #pragma unroll
        for (int i = 0; i < 4; ++i){
          int row = m*16 + 4*l4 + i;
          sRB[row*RBS + colN] = f2bf(fmaxf(acc[m][i] + bb1, 0.f));
        }
    }
    __syncthreads();

    // ============ P2: MLP L2  K=128 -> N=64, out -> sRC as bf16 ============
    {
      unsigned short* A2 = (unsigned short*)sRC;
      f32x4 acc[4];
      #pragma unroll
      for (int mm = 0; mm < 4; ++mm) acc[mm] = z4;
      #pragma unroll
      for (int kt = 0; kt < 4; ++kt){
        #pragma unroll
        for (int mm = 0; mm < 4; ++mm){
          if (mm < mc2){
            s16x8 af = *(const s16x8*)&sRB[((m02+mm)*16 + l15)*RBS + kt*32 + 8*l4];
            acc[mm] = mfma16(af, w2f[kt], acc[mm]);
          }
        }
      }
      #pragma unroll
      for (int mm = 0; mm < 4; ++mm){
        if (mm < mc2){
          #pragma unroll
          for (int i = 0; i < 4; ++i){
            int row = (m02+mm)*16 + 4*l4 + i;
            A2[row*IVS + col2] = f2bf(fmaxf(acc[mm][i] + bb2, 0.f));
          }
        }
      }
    }
    __syncthreads();

    // ============ P3: MLP L3  K=64 -> N=32, out -> sRB (acts3) ============
    {
      const unsigned short* A2 = (const unsigned short*)sRC;
      f32x4 acc[2];
      acc[0] = z4; acc[1] = z4;
      #pragma unroll
      for (int kt = 0; kt < 2; ++kt){
        #pragma unroll
        for (int mm = 0; mm < 2; ++mm){
          if (mm < mc3){
            s16x8 af = *(const s16x8*)&A2[((m03+mm)*16 + l15)*IVS + kt*32 + 8*l4];
            acc[mm] = mfma16(af, w3f[kt], acc[mm]);
          }
        }
      }
      #pragma unroll
      for (int mm = 0; mm < 2; ++mm){
        if (mm < mc3){
          #pragma unroll
          for (int i = 0; i < 4; ++i){
            int row = (m03+mm)*16 + 4*l4 + i;
            sRB[row*RBS + col3] = f2bf(fmaxf(acc[mm][i] + bb3, 0.f));
          }
        }
      }
    }
    __syncthreads();

    // ============ P4: MLP L4  K=32 -> N=128, + eps, -> sXf, fused mean ============
    {
      f32x4 acc[7];
      #pragma unroll
      for (int m = 0; m < 7; ++m) acc[m] = z4;
      s16x8 af[7];
      #pragma unroll
      for (int m = 0; m < 7; ++m)
        af[m] = *(const s16x8*)&sRB[(m*16 + l15)*RBS + 8*l4];
      #pragma unroll
      for (int m = 0; m < 7; ++m) acc[m] = mfma16(af[m], w4f, acc[m]);

      float part = 0.f;
      #pragma unroll
      for (int m = 0; m < 7; ++m)
        #pragma unroll
        for (int i = 0; i < 4; ++i){
          int row = m*16 + 4*l4 + i;
          if (row < NMCC){
            float v = acc[m][i] + bb4 + 0.05f*ev[m][i];
            sXf[row*XFS + colN] = v;
            part += v;
          }
        }
      // reduce partial sums over the 4 l4-groups (lanes xor 16, 32)
      part += __shfl_xor(part, 16);
      part += __shfl_xor(part, 32);
      if (l4 == 0) sXm[colN] = part * 0.01f;
    }
    __syncthreads();

    // ============ P5: XcT pack + y/ypv/r ============
    if (tid < 64){
      float ypv = y_r + 0.1f*ny_r;
      float rv  = y_r - sXm[tid];
      sYpv[tid] = ypv;
      sRv[tid]  = rv;
      sRC[tid*RCS + 128] = rv;          // rhs column for the solve
    }
    #pragma unroll
    for (int q = 0; q < 4; ++q){
      int d0 = wid*16 + q*4;
      f32x4 xm = *(const f32x4*)&sXm[d0];
      #pragma unroll
      for (int pass = 0; pass < 2; ++pass){
        int n = pass*64 + lane;
        float v0, v1, v2, v3;
        if (n < NMCC){
          f32x4 xv = *(const f32x4*)&sXf[n*XFS + d0];
          v0 = xv[0]-xm[0]; v1 = xv[1]-xm[1]; v2 = xv[2]-xm[2]; v3 = xv[3]-xm[3];
        } else { v0 = v1 = v2 = v3 = 0.f; }
        sRB[(d0+0)*RBS + n] = f2bf(v0);
        sRB[(d0+1)*RBS + n] = f2bf(v1);
        sRB[(d0+2)*RBS + n] = f2bf(v2);
        sRB[(d0+3)*RBS + n] = f2bf(v3);
      }
    }
    __syncthreads();

    // ============ P6: cov HP = taper .* (XcT@Xc), fused S assembly ============
    {
      f32x4 cacc[4];
      #pragma unroll
      for (int mt = 0; mt < 4; ++mt) cacc[mt] = z4;
      #pragma unroll
      for (int kt = 0; kt < 4; ++kt){
        s16x8 caf[4];
        #pragma unroll
        for (int mt = 0; mt < 4; ++mt)
          caf[mt] = *(const s16x8*)&sRB[(mt*16 + l15)*RBS + kt*32 + 8*l4];
        s16x8 cbf = *(const s16x8*)&sRB[colN*RBS + kt*32 + 8*l4];
        #pragma unroll
        for (int mt = 0; mt < 4; ++mt) cacc[mt] = mfma16(caf[mt], cbf, cacc[mt]);
      }
      #pragma unroll
      for (int mt = 0; mt < 4; ++mt)
        #pragma unroll
        for (int i = 0; i < 4; ++i){
          int row = mt*16 + 4*l4 + i;
          float v = cacc[mt][i] * tv[mt][i];
          sRC[row*RCS + colN] = v;
          if (wid < 4) sRD[row*65 + colN] = v + ((row == colN) ? 0.01f : 0.f);
        }
    }
    __syncthreads();

    // ============ P7: eps(t+1) prefetch ; chol (w0) || innov pack (w1-7) ============
    if (t + 1 < TC){
      #pragma unroll
      for (int m = 0; m < 7; ++m)
        #pragma unroll
        for (int i = 0; i < 4; ++i){
          int row = m*16 + 4*l4 + i;
          if (row < NMCC)
            ev[m][i] = epss[((size_t)((t+1)*NMCC + row)*BC + b)*DXC + colN];
        }
    }
    if (wid == 0){
      // banded Cholesky, half-bandwidth 9
      for (int j = 0; j < 64; ++j){
        __threadfence_block();
        float piv  = sRD[j*65 + j];
        float rd   = 1.0f / sqrtf(piv);
        float rpiv = rd * rd;
        if (lane == 0){ sRdiag[j] = rd; ldet_t += 0.5f * logf(piv); }
        if (lane < 9){
          int i = j + 1 + lane;
          sLb[j*12 + lane] = (i < 64) ? sRD[i*65 + j] * rd : 0.f;
        }
        {
          int i = j + 1 + di1, k = j + 1 + dk1;
          if (i < 64 && k < 64)
            sRD[i*65 + k] -= sRD[i*65 + j] * sRD[k*65 + j] * rpiv;
        }
        if (has2){
          int i = j + 1 + di2, k = j + 1 + dk2;
          if (i < 64 && k < 64)
            sRD[i*65 + k] -= sRD[i*65 + j] * sRD[k*65 + j] * rpiv;
        }
      }
    } else {
      // innovation pack: (y_pert - X) bf16 -> sRB stride IVS
      int r0 = (wid - 1)*16 + (lane >> 2);
      int c0 = (lane & 3)*16;
      if (r0 < NMCC){
        #pragma unroll
        for (int ii = 0; ii < 4; ++ii){
          f32x4 xv = *(const f32x4*)&sXf[r0*XFS + c0 + ii*4];
          unsigned long long pk =
              (unsigned long long)f2bf(sYpv[c0+ii*4+0] - xv[0])
            | ((unsigned long long)f2bf(sYpv[c0+ii*4+1] - xv[1]) << 16)
            | ((unsigned long long)f2bf(sYpv[c0+ii*4+2] - xv[2]) << 32)
            | ((unsigned long long)f2bf(sYpv[c0+ii*4+3] - xv[3]) << 48);
          *(unsigned long long*)&sRB[r0*IVS + c0 + ii*4] = pk;
        }
      } else {
        #pragma unroll
        for (int ii = 0; ii < 4; ++ii)
          *(unsigned long long*)&sRB[r0*IVS + c0 + ii*4] = 0ULL;
      }
    }
    __syncthreads();

    // ============ P8: band triangular solves on 129 columns ============
    {
      int c = tid;
      if (c < 129){
        float w0 = sRC[0*RCS + c], w1 = sRC[1*RCS + c], w2 = sRC[2*RCS + c];
        float w3 = sRC[3*RCS + c], w4 = sRC[4*RCS + c], w5 = sRC[5*RCS + c];
        float w6 = sRC[6*RCS + c], w7 = sRC[7*RCS + c], w8 = sRC[8*RCS + c];
        float w9 = sRC[9*RCS + c];
        float z2l = 0.f;
        for (int j = 0; j < 64; ++j){
          float z = w0 * sRdiag[j];
          sRC[j*RCS + c] = z;
          z2l += z * z;
          const float* lb = &sLb[j*12];
          w0 = w1 - lb[0]*z; w1 = w2 - lb[1]*z; w2 = w3 - lb[2]*z;
          w3 = w4 - lb[3]*z; w4 = w5 - lb[4]*z; w5 = w6 - lb[5]*z;
          w6 = w7 - lb[6]*z; w7 = w8 - lb[7]*z; w8 = w9 - lb[8]*z;
          int jn = j + 10;
          w9 = (jn < 64) ? sRC[jn*RCS + c] : 0.f;
        }
        if (c == 128) sSc[0] = z2l;
        float x1=0.f,x2=0.f,x3=0.f,x4=0.f,x5=0.f,x6=0.f,x7=0.f,x8=0.f,x9=0.f;
        for (int j = 63; j >= 0; --j){
          const float* lb = &sLb[j*12];
          float acc = sRC[j*RCS + c]
            - lb[0]*x1 - lb[1]*x2 - lb[2]*x3 - lb[3]*x4 - lb[4]*x5
            - lb[5]*x6 - lb[6]*x7 - lb[7]*x8 - lb[8]*x9;
          float xj = acc * sRdiag[j];
          sRC[j*RCS + c] = xj;
          x9=x8; x8=x7; x7=x6; x6=x5; x5=x4; x4=x3; x3=x2; x2=x1; x1=xj;
        }
      }
    }
    __syncthreads();

    // ============ P9: KT pack + posterior means + ll ============
    {
      unsigned short* KT = (unsigned short*)sRD;
      #pragma unroll
      for (int q = 0; q < 4; ++q){
        int e0 = wid*16 + q*4;
        f32x4 kv = *(const f32x4*)&sRC[lane*RCS + e0];
        KT[(e0+0)*KTS + lane] = f2bf(kv[0]);
        KT[(e0+1)*KTS + lane] = f2bf(kv[1]);
        KT[(e0+2)*KTS + lane] = f2bf(kv[2]);
        KT[(e0+3)*KTS + lane] = f2bf(kv[3]);
      }
    }
    if (tid < 128){
      float s = sXm[tid];
      #pragma unroll 4
      for (int o = 0; o < 64; ++o) s += sRv[o] * sRC[o*RCS + tid];
      out_means[(t*BC + b)*DXC + tid] = s;
    }
    if (tid == 0){
      llsum += -0.5f*sSc[0] - ldet_t - 58.812066f;
    }
    __syncthreads();

    // ============ P10: update Xf += innov @ K ============
    {
      const unsigned short* IV = sRB;
      const unsigned short* KT = (const unsigned short*)sRD;
      f32x4 uacc[7];
      #pragma unroll
      for (int m = 0; m < 7; ++m) uacc[m] = z4;
      #pragma unroll
      for (int kt = 0; kt < 2; ++kt){
        s16x8 af[7];
        #pragma unroll
        for (int m = 0; m < 7; ++m)
          af[m] = *(const s16x8*)&IV[(m*16 + l15)*IVS + kt*32 + 8*l4];
        s16x8 bf = *(const s16x8*)&KT[colN*KTS + kt*32 + 8*l4];
        #pragma unroll
        for (int m = 0; m < 7; ++m) uacc[m] = mfma16(af[m], bf, uacc[m]);
      }
      #pragma unroll
      for (int m = 0; m < 7; ++m)
        #pragma unroll
        for (int i = 0; i < 4; ++i){
          int row = m*16 + 4*l4 + i;
          if (row < NMCC) sXf[row*XFS + colN] += uacc[m][i];
        }
    }
    __syncthreads();
  } // t loop

  if (tid == 0) llp[b] = llsum;
}

// ---------------- final: elbo = -mean(kl) + sum_t mean_b ll ----------------
__global__ void final_kernel(const float* __restrict__ klp, const float* __restrict__ llp,
                             float* __restrict__ out){
  __shared__ float s1[128], s2[128];
  int tid = threadIdx.x;
  s1[tid] = klp[tid];
  s2[tid] = llp[tid];
  __syncthreads();
  if (tid == 0){
    float a = 0.f, c = 0.f;
    for (int i = 0; i < 128; ++i){ a += s1[i]; c += s2[i]; }
    out[0] = -a/128.f + c/128.f;
  }
}

extern "C" void kernel_launch(void* const* d_in, const int* in_sizes, int n_in,
                              void* d_out, int out_size, void* d_ws, size_t ws_size,
                              hipStream_t stream){
  (void)in_sizes; (void)n_in; (void)out_size; (void)ws_size;
  const float* obs  = (const float*)d_in[0];
  const float* W1   = (const float*)d_in[1];
  const float* b1   = (const float*)d_in[2];
  const float* W2   = (const float*)d_in[3];
  const float* b2   = (const float*)d_in[4];
  const float* W3   = (const float*)d_in[5];
  const float* b3   = (const float*)d_in[6];
  const float* W4   = (const float*)d_in[7];
  const float* b4   = (const float*)d_in[8];
  const float* Wih  = (const float*)d_in[9];
  const float* Whh  = (const float*)d_in[10];
  const float* bih  = (const float*)d_in[11];
  const float* Wm   = (const float*)d_in[12];
  const float* bm   = (const float*)d_in[13];
  const float* Wv   = (const float*)d_in[14];
  const float* bv   = (const float*)d_in[15];
  const float* eps0 = (const float*)d_in[16];
  const float* epss = (const float*)d_in[17];
  const float* nsy  = (const float*)d_in[18];

  char* ws = (char*)d_ws;
  float* gin   = (float*)(ws + 0);           // 50*128*256*4 = 6,553,600 B
  float* qmean = (float*)(ws + 6553600);     // 128*128*4
  float* qstd  = (float*)(ws + 6619136);
  float* klp   = (float*)(ws + 6684672);
  float* llp   = (float*)(ws + 6685184);

  float* out = (float*)d_out;

  hipLaunchKernelGGL(gin_kernel, dim3(TC*BC), dim3(256), 0, stream,
                     obs, Wih, bih, gin);
  hipLaunchKernelGGL(lstm_kernel, dim3(BC), dim3(256), 0, stream,
                     gin, Whh, Wm, bm, Wv, bv, qmean, qstd, klp);
  hipLaunchKernelGGL(enkf_kernel, dim3(BC), dim3(NTHREADS), 0, stream,
                     obs, W1, b1, W2, b2, W3, b3, W4, b4,
                     eps0, epss, nsy, qmean, qstd, out + 1, llp);
  hipLaunchKernelGGL(final_kernel, dim3(1), dim3(128), 0, stream, klp, llp, out);
}

// Round 3
// 2271.104 us; speedup vs baseline: 1.4181x; 1.0982x over previous
//
#include <hip/hip_runtime.h>

#define TC   50
#define BC   128
#define DXC  128
#define DYC  64
#define NMCC 100
#define XBS  136   // sU stride (shorts): Xbf [112][136] / XcT [128][136]
#define A1S  136   // acts1 stride
#define A2S  72    // acts2 / innov stride
#define A3S  40    // acts3 stride
#define IVS  72
#define KTS  72
#define HPS  20    // banded HP stride (f32)
#define LBS  12    // band L stride (f32)
#define ZSS  67    // z-scratch stride (f32, odd-ish to avoid bank conflicts)

typedef float f32x4 __attribute__((ext_vector_type(4)));
typedef short s16x8 __attribute__((ext_vector_type(8)));

__device__ __forceinline__ unsigned short f2bf(float x){
  unsigned int u = __float_as_uint(x);
  u += 0x7fffu + ((u >> 16) & 1u);
  return (unsigned short)(u >> 16);
}

__device__ __forceinline__ unsigned int pk2bf(float lo, float hi){
  unsigned int r;
  asm volatile("v_cvt_pk_bf16_f32 %0, %1, %2" : "=v"(r) : "v"(lo), "v"(hi));
  return r;
}

__device__ __forceinline__ f32x4 mfma16(s16x8 a, s16x8 b, f32x4 c){
  return __builtin_amdgcn_mfma_f32_16x16x32_bf16(a, b, c, 0, 0, 0);
}

__device__ __forceinline__ s16x8 packA8(const float* p){
  f32x4 a = *(const f32x4*)p;
  f32x4 c = *(const f32x4*)(p + 4);
  s16x8 r;
  r[0]=(short)f2bf(a[0]); r[1]=(short)f2bf(a[1]);
  r[2]=(short)f2bf(a[2]); r[3]=(short)f2bf(a[3]);
  r[4]=(short)f2bf(c[0]); r[5]=(short)f2bf(c[1]);
  r[6]=(short)f2bf(c[2]); r[7]=(short)f2bf(c[3]);
  return r;
}

__device__ __forceinline__ float gc_taper(int row, int col){
  int dd = row - col; if (dd < 0) dd = -dd;
  if (128 - dd < dd) dd = 128 - dd;
  double z = (double)dd / 5.0;
  double g = 0.0;
  if (z < 1.0){
    g = 1.0 - (5.0/3.0)*z*z + (5.0/8.0)*z*z*z + 0.5*z*z*z*z - 0.25*z*z*z*z*z;
  } else if (z < 2.0){
    g = 4.0 - 5.0*z + (5.0/3.0)*z*z + (5.0/8.0)*z*z*z - 0.5*z*z*z*z
        + (1.0/12.0)*z*z*z*z*z - 2.0/(3.0*z);
  }
  return (float)(g / 99.0);   // fold 1/(NMC-1)
}

// ---------------- gin: obs @ Wih^T + bih for all (t,b) ----------------
__global__ __launch_bounds__(256) void gin_kernel(const float* __restrict__ obs,
                          const float* __restrict__ Wih, const float* __restrict__ bih,
                          float* __restrict__ gin){
  __shared__ float xrow[64];
  int blk = blockIdx.x;
  int t = blk / BC, b = blk % BC;
  int tid = threadIdx.x;
  if (tid < 64) xrow[tid] = obs[(b*TC + t)*DYC + tid];
  __syncthreads();
  float s = bih[tid];
  #pragma unroll
  for (int k = 0; k < 64; k += 4){
    f32x4 wv = *(const f32x4*)&Wih[tid*64 + k];
    s += wv[0]*xrow[k] + wv[1]*xrow[k+1] + wv[2]*xrow[k+2] + wv[3]*xrow[k+3];
  }
  gin[blk*256 + tid] = s;
}

// ---------------- lstm: recurrent part + q heads + kl ----------------
__global__ __launch_bounds__(256,1) void lstm_kernel(const float* __restrict__ gin,
     const float* __restrict__ Whh,
     const float* __restrict__ Wm, const float* __restrict__ bm,
     const float* __restrict__ Wv, const float* __restrict__ bv,
     float* __restrict__ qmean, float* __restrict__ qstd, float* __restrict__ klp){
  __shared__ float h[64], cc[64], graw[256], red[128];
  int b = blockIdx.x, tid = threadIdx.x;
  float w[64];
  #pragma unroll
  for (int k = 0; k < 64; k += 4){
    f32x4 v = *(const f32x4*)&Whh[tid*64 + k];
    w[k]=v[0]; w[k+1]=v[1]; w[k+2]=v[2]; w[k+3]=v[3];
  }
  if (tid < 64){ h[tid] = 0.f; cc[tid] = 0.f; }
  __syncthreads();
  for (int t = 0; t < TC; ++t){
    float g = gin[(t*BC + b)*256 + tid];
    #pragma unroll
    for (int k = 0; k < 64; k += 4){
      f32x4 hv = *(const f32x4*)&h[k];
      g += hv[0]*w[k] + hv[1]*w[k+1] + hv[2]*w[k+2] + hv[3]*w[k+3];
    }
    graw[tid] = g;
    __syncthreads();
    if (tid < 64){
      float ig = 1.f/(1.f + expf(-graw[tid]));
      float fg = 1.f/(1.f + expf(-graw[64 + tid]));
      float gg = tanhf(graw[128 + tid]);
      float og = 1.f/(1.f + expf(-graw[192 + tid]));
      float cn = fg*cc[tid] + ig*gg;
      cc[tid] = cn;
      h[tid] = og*tanhf(cn);
    }
    __syncthreads();
  }
  if (tid < 128){
    float sm_ = bm[tid], sv_ = bv[tid];
    #pragma unroll
    for (int k = 0; k < 64; k += 4){
      f32x4 wmv = *(const f32x4*)&Wm[tid*64 + k];
      f32x4 wvv = *(const f32x4*)&Wv[tid*64 + k];
      f32x4 hv  = *(const f32x4*)&h[k];
      sm_ += wmv[0]*hv[0] + wmv[1]*hv[1] + wmv[2]*hv[2] + wmv[3]*hv[3];
      sv_ += wvv[0]*hv[0] + wvv[1]*hv[1] + wvv[2]*hv[2] + wvv[3]*hv[3];
    }
    float qv = ((sv_ > 20.f) ? sv_ : log1pf(expf(sv_))) + 1e-4f;
    qmean[b*DXC + tid] = sm_;
    qstd[b*DXC + tid]  = sqrtf(qv);
    red[tid] = 0.5f*(qv + sm_*sm_ - 1.f - logf(qv));
  }
  __syncthreads();
  if (tid == 0){
    float s = 0.f;
    for (int i = 0; i < 128; ++i) s += red[i];
    klp[b] = s;
  }
}

// ---------------- EnKF megakernel: one block (8 waves) per batch b ----------------
__global__ __launch_bounds__(512,1) void enkf_kernel(
    const float* __restrict__ obs,
    const float* __restrict__ W1, const float* __restrict__ b1g,
    const float* __restrict__ W2, const float* __restrict__ b2g,
    const float* __restrict__ W3, const float* __restrict__ b3g,
    const float* __restrict__ W4, const float* __restrict__ b4g,
    const float* __restrict__ eps0, const float* __restrict__ epss,
    const float* __restrict__ nsyg,
    const float* __restrict__ qmean, const float* __restrict__ qstd,
    float* __restrict__ out_means, float* __restrict__ llp)
{
  __shared__ unsigned short sU[128*XBS];   // Xbf [112][136] / XcT [128][136] / z-scratch f32
  __shared__ unsigned short sA[112*A1S];   // acts1 / acts3 / KT
  __shared__ unsigned short sB[112*A2S];   // acts2 / innov
  __shared__ float sHPb[64*HPS];           // banded HP (linear part)
  __shared__ float sW9[9*12];              // wrap corner HP[o][119+w]
  __shared__ float sLb[64*LBS];            // band L (in-place chol); [j][0]=rd, [j][1..9]=L
  __shared__ float sXm[DXC];
  __shared__ float sRv[DYC];
  __shared__ float sSc[4];

  const int b    = blockIdx.x;
  const int tid  = threadIdx.x;
  const int lane = tid & 63;
  const int wid  = tid >> 6;          // 0..7
  const int l15  = lane & 15;
  const int l4   = lane >> 4;

  const int colN = wid*16 + l15;
  const int col2 = (wid & 3)*16 + l15;
  const int col3 = (wid & 1)*16 + l15;
  const int m02  = (wid >> 2) * 4;
  const int mc2  = (wid >> 2) ? 3 : 4;
  const int m03  = (wid >> 1) * 2;
  const int mc3  = ((wid >> 1) == 3) ? 1 : 2;

  // ---- hoisted weight fragments ----
  s16x8 w1f[4], w2f[4], w3f[2], w4f;
  #pragma unroll
  for (int kt = 0; kt < 4; ++kt) w1f[kt] = packA8(&W1[colN*128 + kt*32 + 8*l4]);
  #pragma unroll
  for (int kt = 0; kt < 4; ++kt) w2f[kt] = packA8(&W2[col2*128 + kt*32 + 8*l4]);
  #pragma unroll
  for (int kt = 0; kt < 2; ++kt) w3f[kt] = packA8(&W3[col3*64 + kt*32 + 8*l4]);
  w4f = packA8(&W4[colN*32 + 8*l4]);
  const float bb1 = b1g[colN], bb2 = b2g[col2], bb3 = b3g[col3], bb4 = b4g[colN];

  // ---- cov tile assignment (12 band tiles over 8 waves) ----
  const int mt1 = (0x22111000u >> (4*wid)) & 15;
  const int nt1 = (0x21210710u >> (4*wid)) & 15;
  const int mt2 = (0x3332u >> (4*wid)) & 15;   // valid for wid<4
  const int nt2 = (0x4323u >> (4*wid)) & 15;
  float tv1[4], tv2[4];
  #pragma unroll
  for (int i = 0; i < 4; ++i){
    tv1[i] = gc_taper(mt1*16 + 4*l4 + i, nt1*16 + l15);
    tv2[i] = (wid < 4) ? gc_taper(mt2*16 + 4*l4 + i, nt2*16 + l15) : 0.f;
  }

  // ---- chol pair assignment: 45 pairs (1<=dk<=di<=9) ----
  int di1 = 1, dk1 = 1;
  { int pp = lane;
    #pragma unroll
    for (int dd = 1; dd <= 9; ++dd){ if (pp < dd){ di1 = dd; dk1 = pp + 1; break; } pp -= dd; } }
  const bool cact = (lane < 45);

  // ---- x0 into registers + bf16 mirror ----
  float xreg[7][4];
  {
    float qm = qmean[b*DXC + colN], qs = qstd[b*DXC + colN];
    #pragma unroll
    for (int m = 0; m < 7; ++m)
      #pragma unroll
      for (int i = 0; i < 4; ++i){
        int row = m*16 + 4*l4 + i;
        float v = 0.f;
        if (row < NMCC) v = qm + qs * eps0[((size_t)row*BC + b)*DXC + colN];
        xreg[m][i] = v;
        if (row < NMCC) sU[row*XBS + colN] = f2bf(v);
      }
    for (int idx = tid; idx < 12*128; idx += 512)
      sU[(100 + (idx >> 7))*XBS + (idx & 127)] = 0;
  }
  // ---- prefetch eps for t=0 ----
  float ev[7][4];
  #pragma unroll
  for (int m = 0; m < 7; ++m)
    #pragma unroll
    for (int i = 0; i < 4; ++i){
      int row = m*16 + 4*l4 + i;
      ev[m][i] = (row < NMCC) ? epss[((size_t)row*BC + b)*DXC + colN] : 0.f;
    }
  __syncthreads();

  float llsum = 0.f;
  const f32x4 z4 = {0.f, 0.f, 0.f, 0.f};

  for (int t = 0; t < TC; ++t){
    float ldet_t = 0.f;

    // ============ P1: MLP L1  [112,128]x[128,128] -> sA (acts1) ============
    {
      f32x4 acc[7];
      #pragma unroll
      for (int m = 0; m < 7; ++m) acc[m] = z4;
      #pragma unroll
      for (int kt = 0; kt < 4; ++kt){
        #pragma unroll
        for (int m = 0; m < 7; ++m){
          s16x8 af = *(const s16x8*)&sU[(m*16 + l15)*XBS + kt*32 + 8*l4];
          acc[m] = mfma16(af, w1f[kt], acc[m]);
        }
      }
      #pragma unroll
      for (int m = 0; m < 7; ++m)
        #pragma unroll
        for (int i = 0; i < 4; ++i){
          int row = m*16 + 4*l4 + i;
          sA[row*A1S + colN] = f2bf(fmaxf(acc[m][i] + bb1, 0.f));
        }
    }
    __syncthreads();

    // ============ P2: MLP L2  K=128 -> N=64 -> sB (acts2 bf16) ============
    {
      f32x4 acc[4];
      #pragma unroll
      for (int mm = 0; mm < 4; ++mm) acc[mm] = z4;
      #pragma unroll
      for (int kt = 0; kt < 4; ++kt){
        #pragma unroll
        for (int mm = 0; mm < 4; ++mm){
          if (mm < mc2){
            s16x8 af = *(const s16x8*)&sA[((m02+mm)*16 + l15)*A1S + kt*32 + 8*l4];
            acc[mm] = mfma16(af, w2f[kt], acc[mm]);
          }
        }
      }
      #pragma unroll
      for (int mm = 0; mm < 4; ++mm){
        if (mm < mc2){
          #pragma unroll
          for (int i = 0; i < 4; ++i){
            int row = (m02+mm)*16 + 4*l4 + i;
            sB[row*A2S + col2] = f2bf(fmaxf(acc[mm][i] + bb2, 0.f));
          }
        }
      }
    }
    __syncthreads();

    // ============ P3: MLP L3  K=64 -> N=32 -> sA (acts3) ============
    {
      f32x4 acc[2];
      acc[0] = z4; acc[1] = z4;
      #pragma unroll
      for (int kt = 0; kt < 2; ++kt){
        #pragma unroll
        for (int mm = 0; mm < 2; ++mm){
          if (mm < mc3){
            s16x8 af = *(const s16x8*)&sB[((m03+mm)*16 + l15)*A2S + kt*32 + 8*l4];
            acc[mm] = mfma16(af, w3f[kt], acc[mm]);
          }
        }
      }
      __syncthreads();   // acts1 reads done before overwriting sA low region
      #pragma unroll
      for (int mm = 0; mm < 2; ++mm){
        if (mm < mc3){
          #pragma unroll
          for (int i = 0; i < 4; ++i){
            int row = (m03+mm)*16 + 4*l4 + i;
            sA[row*A3S + col3] = f2bf(fmaxf(acc[mm][i] + bb3, 0.f));
          }
        }
      }
    }
    __syncthreads();

    // ============ P4: MLP L4  K=32 -> N=128 + eps -> xreg; fused mean ============
    {
      f32x4 acc[7];
      #pragma unroll
      for (int m = 0; m < 7; ++m) acc[m] = z4;
      #pragma unroll
      for (int m = 0; m < 7; ++m){
        s16x8 af = *(const s16x8*)&sA[(m*16 + l15)*A3S + 8*l4];
        acc[m] = mfma16(af, w4f, acc[m]);
      }
      float part = 0.f;
      #pragma unroll
      for (int m = 0; m < 7; ++m)
        #pragma unroll
        for (int i = 0; i < 4; ++i){
          int row = m*16 + 4*l4 + i;
          if (row < NMCC){
            float v = acc[m][i] + bb4 + 0.05f*ev[m][i];
            xreg[m][i] = v;
            part += v;
          } else xreg[m][i] = 0.f;
        }
      part += __shfl_xor(part, 16);
      part += __shfl_xor(part, 32);
      if (l4 == 0) sXm[colN] = part * 0.01f;
    }
    __syncthreads();

    // ============ P5: rv ; XcT pack (from xreg) ; innov pack (from xreg) ============
    if (tid < 64){
      float y = obs[((size_t)b*TC + t)*DYC + tid];
      sRv[tid] = y - sXm[tid];
    }
    if (colN <= 72 || colN >= 119){
      float xm = sXm[colN];
      #pragma unroll
      for (int m = 0; m < 7; ++m){
        float v0, v1, v2, v3;
        if (m == 6 && l4 > 0){ v0 = v1 = v2 = v3 = 0.f; }
        else {
          v0 = xreg[m][0] - xm; v1 = xreg[m][1] - xm;
          v2 = xreg[m][2] - xm; v3 = xreg[m][3] - xm;
        }
        uint2 pk;
        pk.x = pk2bf(v0, v1);
        pk.y = pk2bf(v2, v3);
        *(uint2*)&sU[colN*XBS + m*16 + 4*l4] = pk;
      }
      uint2 zz; zz.x = 0u; zz.y = 0u;
      *(uint2*)&sU[colN*XBS + 112 + 4*l4] = zz;
    }
    if (wid < 4){
      float ypv = obs[((size_t)b*TC + t)*DYC + colN]
                + 0.1f*nsyg[((size_t)t*BC + b)*DYC + colN];
      #pragma unroll
      for (int m = 0; m < 7; ++m)
        #pragma unroll
        for (int i = 0; i < 4; ++i){
          int row = m*16 + 4*l4 + i;
          if (row < NMCC) sB[row*IVS + colN] = f2bf(ypv - xreg[m][i]);
        }
    }
    __syncthreads();

    // ============ P6: banded cov tiles: HP = taper .* (XcT@Xc) ============
    {
      f32x4 a1 = z4, a2 = z4;
      #pragma unroll
      for (int kt = 0; kt < 4; ++kt){
        s16x8 fa1 = *(const s16x8*)&sU[(mt1*16 + l15)*XBS + kt*32 + 8*l4];
        s16x8 fb1 = *(const s16x8*)&sU[(nt1*16 + l15)*XBS + kt*32 + 8*l4];
        a1 = mfma16(fa1, fb1, a1);
        if (wid < 4){
          s16x8 fa2 = *(const s16x8*)&sU[(mt2*16 + l15)*XBS + kt*32 + 8*l4];
          s16x8 fb2 = *(const s16x8*)&sU[(nt2*16 + l15)*XBS + kt*32 + 8*l4];
          a2 = mfma16(fa2, fb2, a2);
        }
      }
      #pragma unroll
      for (int i = 0; i < 4; ++i){
        int o = mt1*16 + 4*l4 + i, e = nt1*16 + l15;
        float v = a1[i] * tv1[i];
        if (nt1 != 7){
          int dd = e - o;
          if (dd >= -9 && dd <= 9) sHPb[o*HPS + dd + 9] = v;
        } else {
          int w = e - 119;
          if (w >= 0 && o <= w) sW9[o*12 + w] = v;
        }
      }
      if (wid < 4){
        #pragma unroll
        for (int i = 0; i < 4; ++i){
          int o = mt2*16 + 4*l4 + i, e = nt2*16 + l15;
          float v = a2[i] * tv2[i];
          int dd = e - o;
          if (dd >= -9 && dd <= 9) sHPb[o*HPS + dd + 9] = v;
        }
      }
    }
    __syncthreads();

    // ============ P7: eps(t+1) prefetch ; band Cholesky (wave 0) ============
    if (t + 1 < TC){
      #pragma unroll
      for (int m = 0; m < 7; ++m)
        #pragma unroll
        for (int i = 0; i < 4; ++i){
          int row = m*16 + 4*l4 + i;
          if (row < NMCC)
            ev[m][i] = epss[((size_t)((t+1)*NMCC + row)*BC + b)*DXC + colN];
        }
    }
    if (wid == 0){
      // band init: Lb[j][d] = S[j+d][j] = HP[j][j+d] (+0.01 on diag)
      {
        int j = lane;
        #pragma unroll
        for (int d = 0; d < 10; ++d){
          float v = (j + d < 64) ? sHPb[j*HPS + d + 9] : 0.f;
          sLb[j*LBS + d] = v + ((d == 0) ? 0.01f : 0.f);
        }
        #pragma unroll
        for (int d = 10; d < 12; ++d) sLb[j*LBS + d] = 0.f;
      }
      for (int j = 0; j < 64; ++j){
        __threadfence_block();
        float piv = sLb[j*LBS];
        float rdv = rsqrtf(piv);
        if (lane == 0){ ldet_t += 0.5f*logf(piv); sLb[j*LBS] = rdv; }
        if (lane >= 1 && lane <= 9){
          int i2 = j + lane;
          float Lv = (i2 < 64) ? sLb[j*LBS + lane]*rdv : 0.f;
          sLb[j*LBS + lane] = Lv;
        }
        __threadfence_block();
        if (cact){
          int i2 = j + di1;
          if (i2 < 64){
            float Li = sLb[j*LBS + di1];
            float Lk = sLb[j*LBS + dk1];
            sLb[(j + dk1)*LBS + (di1 - dk1)] -= Li*Lk;
          }
        }
      }
    }
    __syncthreads();

    // ============ P8: band solves (83 RHS) -> KT bf16, means, ll ============
    {
      float* zscr = (float*)sU;                       // XcT dead; Xbf rewritten in P10
      unsigned short* KT = (unsigned short*)sA;       // acts dead
      int c = tid;
      if (c < 83){
        int e = (c < 73) ? c : (c + 46);              // 73..81 -> 119..127
        bool isr = (c == 82);
        float w0,w1,w2,w3,w4,w5,w6,w7,w8,w9;
        {
          float wi[10];
          #pragma unroll
          for (int d = 0; d < 10; ++d){
            float bv = 0.f;
            if (isr) bv = sRv[d];
            else if (c < 73){
              int idx = e - d + 9;
              if (idx >= 0 && idx <= 18) bv = sHPb[d*HPS + idx];
            } else {
              int ww = e - 119;
              if (d <= ww) bv = sW9[d*12 + ww];
            }
            wi[d] = bv;
          }
          w0=wi[0]; w1=wi[1]; w2=wi[2]; w3=wi[3]; w4=wi[4];
          w5=wi[5]; w6=wi[6]; w7=wi[7]; w8=wi[8]; w9=wi[9];
        }
        float z2l = 0.f;
        for (int j = 0; j < 64; ++j){
          f32x4 lb0 = *(const f32x4*)&sLb[j*LBS];     // rd, L1, L2, L3
          f32x4 lb4 = *(const f32x4*)&sLb[j*LBS + 4]; // L4..L7
          float  l8 = sLb[j*LBS + 8], l9 = sLb[j*LBS + 9];
          float z = w0 * lb0[0];
          zscr[c*ZSS + j] = z;
          z2l += z*z;
          w0 = w1 - lb0[1]*z; w1 = w2 - lb0[2]*z; w2 = w3 - lb0[3]*z;
          w3 = w4 - lb4[0]*z; w4 = w5 - lb4[1]*z; w5 = w6 - lb4[2]*z;
          w6 = w7 - lb4[3]*z; w7 = w8 - l8*z;     w8 = w9 - l9*z;
          int jn = j + 10;
          float bv = 0.f;
          if (isr){ if (jn < 64) bv = sRv[jn]; }
          else if (c < 73){
            if (jn < 64 && j >= e - 19 && j <= e - 1) bv = sHPb[jn*HPS + (e - j - 1)];
          }
          w9 = bv;
        }
        if (isr) sSc[0] = z2l;
        float x1=0.f,x2=0.f,x3=0.f,x4=0.f,x5=0.f,x6=0.f,x7=0.f,x8=0.f,x9=0.f;
        float macc = 0.f, xodd = 0.f;
        for (int j = 63; j >= 0; --j){
          f32x4 lb0 = *(const f32x4*)&sLb[j*LBS];
          f32x4 lb4 = *(const f32x4*)&sLb[j*LBS + 4];
          float  l8 = sLb[j*LBS + 8], l9 = sLb[j*LBS + 9];
          float acc = zscr[c*ZSS + j]
            - lb0[1]*x1 - lb0[2]*x2 - lb0[3]*x3
            - lb4[0]*x4 - lb4[1]*x5 - lb4[2]*x6 - lb4[3]*x7
            - l8*x8 - l9*x9;
          float xj = acc * lb0[0];
          if (!isr){
            macc += sRv[j]*xj;
            if (j & 1) xodd = xj;
            else *(unsigned int*)&KT[e*KTS + j] = pk2bf(xj, xodd);
          }
          x9=x8; x8=x7; x7=x6; x6=x5; x5=x4; x4=x3; x3=x2; x2=x1; x1=xj;
        }
        if (!isr) out_means[((size_t)t*BC + b)*DXC + e] = sXm[e] + macc;
      } else if (c < 129){
        int e = c - 10;                               // 73..118: K columns are zero
        out_means[((size_t)t*BC + b)*DXC + e] = sXm[e];
      }
    }
    __syncthreads();

    // ============ P10: ll ; update xreg += innov @ K ; rewrite Xbf ============
    if (tid == 0){
      llsum += -0.5f*sSc[0] - ldet_t - 58.812066f;    // 0.5*DY*log(2*pi)
    }
    {
      f32x4 uacc[7];
      #pragma unroll
      for (int m = 0; m < 7; ++m) uacc[m] = z4;
      if (wid != 5 && wid != 6){
        const unsigned short* KT = (const unsigned short*)sA;
        #pragma unroll
        for (int kt = 0; kt < 2; ++kt){
          s16x8 bf = *(const s16x8*)&KT[colN*KTS + kt*32 + 8*l4];
          #pragma unroll
          for (int m = 0; m < 7; ++m){
            s16x8 af = *(const s16x8*)&sB[(m*16 + l15)*IVS + kt*32 + 8*l4];
            uacc[m] = mfma16(af, bf, uacc[m]);
          }
        }
      }
      bool upd = ((colN <= 72) || (colN >= 119)) && (wid != 5) && (wid != 6);
      #pragma unroll
      for (int m = 0; m < 7; ++m)
        #pragma unroll
        for (int i = 0; i < 4; ++i){
          int row = m*16 + 4*l4 + i;
          if (row < NMCC){
            float xn = xreg[m][i] + (upd ? uacc[m][i] : 0.f);
            xreg[m][i] = xn;
            sU[row*XBS + colN] = f2bf(xn);
          }
        }
    }
    __syncthreads();
  } // t loop

  if (tid == 0) llp[b] = llsum;
}

// ---------------- final: elbo = -mean(kl) + sum_t mean_b ll ----------------
__global__ void final_kernel(const float* __restrict__ klp, const float* __restrict__ llp,
                             float* __restrict__ out){
  __shared__ float s1[128], s2[128];
  int tid = threadIdx.x;
  s1[tid] = klp[tid];
  s2[tid] = llp[tid];
  __syncthreads();
  if (tid == 0){
    float a = 0.f, c = 0.f;
    for (int i = 0; i < 128; ++i){ a += s1[i]; c += s2[i]; }
    out[0] = -a/128.f + c/128.f;
  }
}

extern "C" void kernel_launch(void* const* d_in, const int* in_sizes, int n_in,
                              void* d_out, int out_size, void* d_ws, size_t ws_size,
                              hipStream_t stream){
  (void)in_sizes; (void)n_in; (void)out_size; (void)ws_size;
  const float* obs  = (const float*)d_in[0];
  const float* W1   = (const float*)d_in[1];
  const float* b1   = (const float*)d_in[2];
  const float* W2   = (const float*)d_in[3];
  const float* b2   = (const float*)d_in[4];
  const float* W3   = (const float*)d_in[5];
  const float* b3   = (const float*)d_in[6];
  const float* W4   = (const float*)d_in[7];
  const float* b4   = (const float*)d_in[8];
  const float* Wih  = (const float*)d_in[9];
  const float* Whh  = (const float*)d_in[10];
  const float* bih  = (const float*)d_in[11];
  const float* Wm   = (const float*)d_in[12];
  const float* bm   = (const float*)d_in[13];
  const float* Wv   = (const float*)d_in[14];
  const float* bv   = (const float*)d_in[15];
  const float* eps0 = (const float*)d_in[16];
  const float* epss = (const float*)d_in[17];
  const float* nsy  = (const float*)d_in[18];

  char* ws = (char*)d_ws;
  float* gin   = (float*)(ws + 0);           // 50*128*256*4 = 6,553,600 B
  float* qmean = (float*)(ws + 6553600);
  float* qstd  = (float*)(ws + 6619136);
  float* klp   = (float*)(ws + 6684672);
  float* llp   = (float*)(ws + 6685184);

  float* out = (float*)d_out;

  hipLaunchKernelGGL(gin_kernel, dim3(TC*BC), dim3(256), 0, stream,
                     obs, Wih, bih, gin);
  hipLaunchKernelGGL(lstm_kernel, dim3(BC), dim3(256), 0, stream,
                     gin, Whh, Wm, bm, Wv, bv, qmean, qstd, klp);
  hipLaunchKernelGGL(enkf_kernel, dim3(BC), dim3(512), 0, stream,
                     obs, W1, b1, W2, b2, W3, b3, W4, b4,
                     eps0, epss, nsy, qmean, qstd, out + 1, llp);
  hipLaunchKernelGGL(final_kernel, dim3(1), dim3(128), 0, stream, klp, llp, out);
}

// Round 4
// 1985.250 us; speedup vs baseline: 1.6223x; 1.1440x over previous
//
#include <hip/hip_runtime.h>

#define TC   50
#define BC   128
#define DXC  128
#define DYC  64
#define NMCC 100
#define XBS  136   // sU stride (shorts): Xbf [112][136] / XcT [128][136]
#define A1S  136   // acts1 stride (sA)
#define A2S  72    // acts2 / innov stride (sB)
#define A3S  40    // acts3 stride (sC)
#define IVS  72
#define KTS  72
#define HPS  20    // banded HP stride (f32)
#define LBS  12    // band L stride (f32): [j][0]=rd, [j][1..9]=L[j+d][j]
#define ZSS  67    // z-scratch stride (f32)

typedef float f32x4 __attribute__((ext_vector_type(4)));
typedef short s16x8 __attribute__((ext_vector_type(8)));

__device__ __forceinline__ unsigned short f2bf(float x){
  unsigned int u = __float_as_uint(x);
  u += 0x7fffu + ((u >> 16) & 1u);
  return (unsigned short)(u >> 16);
}

__device__ __forceinline__ unsigned int pk2bf(float lo, float hi){
  unsigned int r;
  asm volatile("v_cvt_pk_bf16_f32 %0, %1, %2" : "=v"(r) : "v"(lo), "v"(hi));
  return r;
}

__device__ __forceinline__ f32x4 mfma16(s16x8 a, s16x8 b, f32x4 c){
  return __builtin_amdgcn_mfma_f32_16x16x32_bf16(a, b, c, 0, 0, 0);
}

__device__ __forceinline__ s16x8 packA8(const float* p){
  f32x4 a = *(const f32x4*)p;
  f32x4 c = *(const f32x4*)(p + 4);
  s16x8 r;
  r[0]=(short)f2bf(a[0]); r[1]=(short)f2bf(a[1]);
  r[2]=(short)f2bf(a[2]); r[3]=(short)f2bf(a[3]);
  r[4]=(short)f2bf(c[0]); r[5]=(short)f2bf(c[1]);
  r[6]=(short)f2bf(c[2]); r[7]=(short)f2bf(c[3]);
  return r;
}

__device__ __forceinline__ float gc_taper(int row, int col){
  int dd = row - col; if (dd < 0) dd = -dd;
  if (128 - dd < dd) dd = 128 - dd;
  double z = (double)dd / 5.0;
  double g = 0.0;
  if (z < 1.0){
    g = 1.0 - (5.0/3.0)*z*z + (5.0/8.0)*z*z*z + 0.5*z*z*z*z - 0.25*z*z*z*z*z;
  } else if (z < 2.0){
    g = 4.0 - 5.0*z + (5.0/3.0)*z*z + (5.0/8.0)*z*z*z - 0.5*z*z*z*z
        + (1.0/12.0)*z*z*z*z*z - 2.0/(3.0*z);
  }
  return (float)(g / 99.0);   // fold 1/(NMC-1)
}

// ---------------- gin: obs @ Wih^T + bih for all (t,b) ----------------
__global__ __launch_bounds__(256) void gin_kernel(const float* __restrict__ obs,
                          const float* __restrict__ Wih, const float* __restrict__ bih,
                          float* __restrict__ gin){
  __shared__ float xrow[64];
  int blk = blockIdx.x;
  int t = blk / BC, b = blk % BC;
  int tid = threadIdx.x;
  if (tid < 64) xrow[tid] = obs[(b*TC + t)*DYC + tid];
  __syncthreads();
  float s = bih[tid];
  #pragma unroll
  for (int k = 0; k < 64; k += 4){
    f32x4 wv = *(const f32x4*)&Wih[tid*64 + k];
    s += wv[0]*xrow[k] + wv[1]*xrow[k+1] + wv[2]*xrow[k+2] + wv[3]*xrow[k+3];
  }
  gin[blk*256 + tid] = s;
}

// ---------------- lstm: recurrent part + q heads + kl ----------------
__global__ __launch_bounds__(256,1) void lstm_kernel(const float* __restrict__ gin,
     const float* __restrict__ Whh,
     const float* __restrict__ Wm, const float* __restrict__ bm,
     const float* __restrict__ Wv, const float* __restrict__ bv,
     float* __restrict__ qmean, float* __restrict__ qstd, float* __restrict__ klp){
  __shared__ float h[64], cc[64], graw[256], red[128];
  int b = blockIdx.x, tid = threadIdx.x;
  float w[64];
  #pragma unroll
  for (int k = 0; k < 64; k += 4){
    f32x4 v = *(const f32x4*)&Whh[tid*64 + k];
    w[k]=v[0]; w[k+1]=v[1]; w[k+2]=v[2]; w[k+3]=v[3];
  }
  if (tid < 64){ h[tid] = 0.f; cc[tid] = 0.f; }
  __syncthreads();
  for (int t = 0; t < TC; ++t){
    float g = gin[(t*BC + b)*256 + tid];
    #pragma unroll
    for (int k = 0; k < 64; k += 4){
      f32x4 hv = *(const f32x4*)&h[k];
      g += hv[0]*w[k] + hv[1]*w[k+1] + hv[2]*w[k+2] + hv[3]*w[k+3];
    }
    graw[tid] = g;
    __syncthreads();
    if (tid < 64){
      float ig = 1.f/(1.f + expf(-graw[tid]));
      float fg = 1.f/(1.f + expf(-graw[64 + tid]));
      float gg = tanhf(graw[128 + tid]);
      float og = 1.f/(1.f + expf(-graw[192 + tid]));
      float cn = fg*cc[tid] + ig*gg;
      cc[tid] = cn;
      h[tid] = og*tanhf(cn);
    }
    __syncthreads();
  }
  if (tid < 128){
    float sm_ = bm[tid], sv_ = bv[tid];
    #pragma unroll
    for (int k = 0; k < 64; k += 4){
      f32x4 wmv = *(const f32x4*)&Wm[tid*64 + k];
      f32x4 wvv = *(const f32x4*)&Wv[tid*64 + k];
      f32x4 hv  = *(const f32x4*)&h[k];
      sm_ += wmv[0]*hv[0] + wmv[1]*hv[1] + wmv[2]*hv[2] + wmv[3]*hv[3];
      sv_ += wvv[0]*hv[0] + wvv[1]*hv[1] + wvv[2]*hv[2] + wvv[3]*hv[3];
    }
    float qv = ((sv_ > 20.f) ? sv_ : log1pf(expf(sv_))) + 1e-4f;
    qmean[b*DXC + tid] = sm_;
    qstd[b*DXC + tid]  = sqrtf(qv);
    red[tid] = 0.5f*(qv + sm_*sm_ - 1.f - logf(qv));
  }
  __syncthreads();
  if (tid == 0){
    float s = 0.f;
    for (int i = 0; i < 128; ++i) s += red[i];
    klp[b] = s;
  }
}

// ---------------- EnKF megakernel: one block (8 waves) per batch b ----------------
__global__ __launch_bounds__(512,1) void enkf_kernel(
    const float* __restrict__ obs,
    const float* __restrict__ W1, const float* __restrict__ b1g,
    const float* __restrict__ W2, const float* __restrict__ b2g,
    const float* __restrict__ W3, const float* __restrict__ b3g,
    const float* __restrict__ W4, const float* __restrict__ b4g,
    const float* __restrict__ eps0, const float* __restrict__ epss,
    const float* __restrict__ nsyg,
    const float* __restrict__ qmean, const float* __restrict__ qstd,
    float* __restrict__ out_means, float* __restrict__ llp)
{
  __shared__ unsigned short sU[128*XBS];   // Xbf [112][136] / XcT [128][136] / z-scratch f32
  __shared__ unsigned short sA[112*A1S];   // acts1 / KT
  __shared__ unsigned short sB[112*A2S];   // acts2 / innov
  __shared__ unsigned short sC[112*A3S];   // acts3
  __shared__ float sHPb[64*HPS];           // banded HP (linear part)
  __shared__ float sW9[9*12];              // wrap corner HP[o][119+w]
  __shared__ float sLb[64*LBS];            // band L; [j][0]=rd, [j][1..9]=L[j+d][j]
  __shared__ float sXm[DXC];
  __shared__ float sRv[DYC];
  __shared__ float sSc[4];

  const int b    = blockIdx.x;
  const int tid  = threadIdx.x;
  const int lane = tid & 63;
  const int wid  = tid >> 6;          // 0..7
  const int l15  = lane & 15;
  const int l4   = lane >> 4;

  const int colN = wid*16 + l15;
  const int col2 = (wid & 3)*16 + l15;
  const int col3 = (wid & 1)*16 + l15;
  const int m02  = (wid >> 2) * 4;
  const int mc2  = (wid >> 2) ? 3 : 4;
  const int m03  = (wid >> 1) * 2;
  const int mc3  = ((wid >> 1) == 3) ? 1 : 2;

  // ---- hoisted weight fragments ----
  s16x8 w1f[4], w2f[4], w3f[2], w4f;
  #pragma unroll
  for (int kt = 0; kt < 4; ++kt) w1f[kt] = packA8(&W1[colN*128 + kt*32 + 8*l4]);
  #pragma unroll
  for (int kt = 0; kt < 4; ++kt) w2f[kt] = packA8(&W2[col2*128 + kt*32 + 8*l4]);
  #pragma unroll
  for (int kt = 0; kt < 2; ++kt) w3f[kt] = packA8(&W3[col3*64 + kt*32 + 8*l4]);
  w4f = packA8(&W4[colN*32 + 8*l4]);
  const float bb1 = b1g[colN], bb2 = b2g[col2], bb3 = b3g[col3], bb4 = b4g[colN];

  // ---- cov tile assignment (12 band tiles over 8 waves) ----
  const int mt1 = (0x22111000u >> (4*wid)) & 15;
  const int nt1 = (0x21210710u >> (4*wid)) & 15;
  const int mt2 = (0x3332u >> (4*wid)) & 15;   // valid for wid<4
  const int nt2 = (0x4323u >> (4*wid)) & 15;
  float tv1[4], tv2[4];
  #pragma unroll
  for (int i = 0; i < 4; ++i){
    tv1[i] = gc_taper(mt1*16 + 4*l4 + i, nt1*16 + l15);
    tv2[i] = (wid < 4) ? gc_taper(mt2*16 + 4*l4 + i, nt2*16 + l15) : 0.f;
  }

  // ---- systolic chol lane constants: 55 slots (dk,dd), dk in [0,9], dd in [0,9-dk]
  int cdk = 10, cdd = 0;
  { int acc = 0;
    #pragma unroll
    for (int q = 0; q < 10; ++q){
      int cnt = 10 - q;
      if (lane >= acc && lane < acc + cnt){ cdk = q; cdd = lane - acc; }
      acc += cnt;
    } }
  const int ioff_s  = (cdk + cdd > 9) ? 0 : (cdk + cdd);            // broadcast src for c_{i-j}
  const int dk_s    = (cdk > 9) ? 0 : cdk;                          // broadcast src for c_{k-j}
  int baseNext = (cdk + 1)*10 - ((cdk + 1)*cdk)/2;
  const int shsrc   = (baseNext + cdd >= 55) ? 0 : (baseNext + cdd);// shift source lane
  const bool enterSlot = (cdk + cdd == 9) && (cdk <= 9);
  const bool isCol0    = (cdk == 0);

  // ---- x0 into registers + bf16 mirror ----
  float xreg[7][4];
  {
    float qm = qmean[b*DXC + colN], qs = qstd[b*DXC + colN];
    #pragma unroll
    for (int m = 0; m < 7; ++m)
      #pragma unroll
      for (int i = 0; i < 4; ++i){
        int row = m*16 + 4*l4 + i;
        float v = 0.f;
        if (row < NMCC) v = qm + qs * eps0[((size_t)row*BC + b)*DXC + colN];
        xreg[m][i] = v;
        if (row < NMCC) sU[row*XBS + colN] = f2bf(v);
      }
    for (int idx = tid; idx < 12*128; idx += 512)
      sU[(100 + (idx >> 7))*XBS + (idx & 127)] = 0;
  }
  // ---- prefetch eps for t=0 ----
  float ev[7][4];
  #pragma unroll
  for (int m = 0; m < 7; ++m)
    #pragma unroll
    for (int i = 0; i < 4; ++i){
      int row = m*16 + 4*l4 + i;
      ev[m][i] = (row < NMCC) ? epss[((size_t)row*BC + b)*DXC + colN] : 0.f;
    }
  __syncthreads();

  float llsum = 0.f;
  const f32x4 z4 = {0.f, 0.f, 0.f, 0.f};

  for (int t = 0; t < TC; ++t){
    float ldet_t = 0.f;

    // issue y loads early (waves 0-3 own obs cols)
    float y_r = 0.f, ypv = 0.f;
    if (wid < 4){
      y_r = obs[((size_t)b*TC + t)*DYC + colN];
      ypv = y_r + 0.1f*nsyg[((size_t)t*BC + b)*DYC + colN];
    }

    // ============ P1: MLP L1 -> sA (acts1) ============
    {
      f32x4 acc[7];
      #pragma unroll
      for (int m = 0; m < 7; ++m) acc[m] = z4;
      #pragma unroll
      for (int kt = 0; kt < 4; ++kt){
        #pragma unroll
        for (int m = 0; m < 7; ++m){
          s16x8 af = *(const s16x8*)&sU[(m*16 + l15)*XBS + kt*32 + 8*l4];
          acc[m] = mfma16(af, w1f[kt], acc[m]);
        }
      }
      #pragma unroll
      for (int m = 0; m < 7; ++m)
        #pragma unroll
        for (int i = 0; i < 4; ++i){
          int row = m*16 + 4*l4 + i;
          sA[row*A1S + colN] = f2bf(fmaxf(acc[m][i] + bb1, 0.f));
        }
    }
    __syncthreads();

    // ============ P2: MLP L2 -> sB (acts2) ============
    {
      f32x4 acc[4];
      #pragma unroll
      for (int mm = 0; mm < 4; ++mm) acc[mm] = z4;
      #pragma unroll
      for (int kt = 0; kt < 4; ++kt){
        #pragma unroll
        for (int mm = 0; mm < 4; ++mm){
          if (mm < mc2){
            s16x8 af = *(const s16x8*)&sA[((m02+mm)*16 + l15)*A1S + kt*32 + 8*l4];
            acc[mm] = mfma16(af, w2f[kt], acc[mm]);
          }
        }
      }
      #pragma unroll
      for (int mm = 0; mm < 4; ++mm){
        if (mm < mc2){
          #pragma unroll
          for (int i = 0; i < 4; ++i){
            int row = (m02+mm)*16 + 4*l4 + i;
            sB[row*A2S + col2] = f2bf(fmaxf(acc[mm][i] + bb2, 0.f));
          }
        }
      }
    }
    __syncthreads();

    // ============ P3: MLP L3 -> sC (acts3) ============
    {
      f32x4 acc[2];
      acc[0] = z4; acc[1] = z4;
      #pragma unroll
      for (int kt = 0; kt < 2; ++kt){
        #pragma unroll
        for (int mm = 0; mm < 2; ++mm){
          if (mm < mc3){
            s16x8 af = *(const s16x8*)&sB[((m03+mm)*16 + l15)*A2S + kt*32 + 8*l4];
            acc[mm] = mfma16(af, w3f[kt], acc[mm]);
          }
        }
      }
      #pragma unroll
      for (int mm = 0; mm < 2; ++mm){
        if (mm < mc3){
          #pragma unroll
          for (int i = 0; i < 4; ++i){
            int row = (m03+mm)*16 + 4*l4 + i;
            sC[row*A3S + col3] = f2bf(fmaxf(acc[mm][i] + bb3, 0.f));
          }
        }
      }
    }
    __syncthreads();

    // ============ P4: L4 + eps -> xreg; in-reg mean; XcT pack; rv; innov(w0) ============
    {
      f32x4 acc[7];
      #pragma unroll
      for (int m = 0; m < 7; ++m) acc[m] = z4;
      #pragma unroll
      for (int m = 0; m < 7; ++m){
        s16x8 af = *(const s16x8*)&sC[(m*16 + l15)*A3S + 8*l4];
        acc[m] = mfma16(af, w4f, acc[m]);
      }
      float part = 0.f;
      #pragma unroll
      for (int m = 0; m < 7; ++m)
        #pragma unroll
        for (int i = 0; i < 4; ++i){
          int row = m*16 + 4*l4 + i;
          if (row < NMCC){
            float v = acc[m][i] + bb4 + 0.05f*ev[m][i];
            xreg[m][i] = v;
            part += v;
          } else xreg[m][i] = 0.f;
        }
      part += __shfl_xor(part, 16);
      part += __shfl_xor(part, 32);
      float xm = part * 0.01f;            // every lane of the column group has it
      if (l4 == 0) sXm[colN] = xm;
      if (wid < 4 && l4 == 0) sRv[colN] = y_r - xm;

      // XcT pack (cols needed by the cov band only)
      if (colN <= 72 || colN >= 119){
        #pragma unroll
        for (int m = 0; m < 7; ++m){
          float v0, v1, v2, v3;
          if (m == 6 && l4 > 0){ v0 = v1 = v2 = v3 = 0.f; }
          else {
            v0 = xreg[m][0] - xm; v1 = xreg[m][1] - xm;
            v2 = xreg[m][2] - xm; v3 = xreg[m][3] - xm;
          }
          uint2 pk;
          pk.x = pk2bf(v0, v1);
          pk.y = pk2bf(v2, v3);
          *(uint2*)&sU[colN*XBS + m*16 + 4*l4] = pk;
        }
        uint2 zz; zz.x = 0u; zz.y = 0u;
        *(uint2*)&sU[colN*XBS + 112 + 4*l4] = zz;
      }
      // innov pack for wave 0's columns (0..15); waves 1-3 do theirs in P7
      if (wid == 0){
        #pragma unroll
        for (int m = 0; m < 7; ++m)
          #pragma unroll
          for (int i = 0; i < 4; ++i){
            int row = m*16 + 4*l4 + i;
            sB[row*IVS + colN] = (row < NMCC) ? f2bf(ypv - xreg[m][i])
                                              : (unsigned short)0;
          }
      }
    }
    __syncthreads();

    // ============ P6: banded cov tiles: HP = taper .* (XcT@Xc) ============
    {
      f32x4 a1 = z4, a2 = z4;
      #pragma unroll
      for (int kt = 0; kt < 4; ++kt){
        s16x8 fa1 = *(const s16x8*)&sU[(mt1*16 + l15)*XBS + kt*32 + 8*l4];
        s16x8 fb1 = *(const s16x8*)&sU[(nt1*16 + l15)*XBS + kt*32 + 8*l4];
        a1 = mfma16(fa1, fb1, a1);
        if (wid < 4){
          s16x8 fa2 = *(const s16x8*)&sU[(mt2*16 + l15)*XBS + kt*32 + 8*l4];
          s16x8 fb2 = *(const s16x8*)&sU[(nt2*16 + l15)*XBS + kt*32 + 8*l4];
          a2 = mfma16(fa2, fb2, a2);
        }
      }
      #pragma unroll
      for (int i = 0; i < 4; ++i){
        int o = mt1*16 + 4*l4 + i, e = nt1*16 + l15;
        float v = a1[i] * tv1[i];
        if (nt1 != 7){
          int dd = e - o;
          if (dd >= -9 && dd <= 9) sHPb[o*HPS + dd + 9] = v;
        } else {
          int w = e - 119;
          if (w >= 0 && o <= w) sW9[o*12 + w] = v;
        }
      }
      if (wid < 4){
        #pragma unroll
        for (int i = 0; i < 4; ++i){
          int o = mt2*16 + 4*l4 + i, e = nt2*16 + l15;
          float v = a2[i] * tv2[i];
          int dd = e - o;
          if (dd >= -9 && dd <= 9) sHPb[o*HPS + dd + 9] = v;
        }
      }
    }
    __syncthreads();

    // ============ P7: eps(t+1) prefetch ; chol (w0, register-systolic) ∥ innov (w1-3) ============
    if (t + 1 < TC){
      #pragma unroll
      for (int m = 0; m < 7; ++m)
        #pragma unroll
        for (int i = 0; i < 4; ++i){
          int row = m*16 + 4*l4 + i;
          if (row < NMCC)
            ev[m][i] = epss[((size_t)((t+1)*NMCC + row)*BC + b)*DXC + colN];
        }
    }
    if (wid == 0){
      // register-systolic banded Cholesky, half-bandwidth 9.
      // slot (cdk,cdd) holds S[j+cdk+cdd][j+cdk]; dk=0 lanes hold the final column j.
      float v = 0.f;
      if (cdk <= 9) v = sHPb[cdk*HPS + cdd + 9] + ((cdd == 0) ? 0.01f : 0.f);
      for (int j = 0; j < 64; ++j){
        float enter = 0.f;
        if (enterSlot && (j + 10 < 64))
          enter = sHPb[(j + 10 - cdd)*HPS + cdd + 9] + ((cdd == 0) ? 0.01f : 0.f);
        float upiv = __shfl(v, 0);
        float u1   = __shfl(v, ioff_s);
        float u2   = __shfl(v, dk_s);
        float rd   = rsqrtf(upiv);
        float rpiv = rd * rd;
        if (isCol0){
          sLb[j*LBS + cdd] = (cdd == 0) ? rd : v * rd;
        }
        if (lane == 0) ldet_t += 0.5f * logf(upiv);
        float vu = (cdk >= 1) ? v - u1*u2*rpiv : v;
        float vs = __shfl(vu, shsrc);
        v = enterSlot ? enter : vs;
      }
    } else if (wid < 4){
      // innovation pack for cols 16..63
      #pragma unroll
      for (int m = 0; m < 7; ++m)
        #pragma unroll
        for (int i = 0; i < 4; ++i){
          int row = m*16 + 4*l4 + i;
          sB[row*IVS + colN] = (row < NMCC) ? f2bf(ypv - xreg[m][i])
                                            : (unsigned short)0;
        }
    }
    __syncthreads();

    // ============ P8: band solves (83 RHS) -> KT bf16, means, ll ============
    {
      float* zscr = (float*)sU;                       // XcT dead; Xbf rewritten in P10
      unsigned short* KT = (unsigned short*)sA;       // acts1 dead
      int c = tid;
      if (c < 83){
        int e = (c < 73) ? c : (c + 46);              // 73..81 -> 119..127
        bool isr = (c == 82);
        float w0,w1,w2,w3,w4,w5,w6,w7,w8,w9;
        {
          float wi[10];
          #pragma unroll
          for (int d = 0; d < 10; ++d){
            float bv = 0.f;
            if (isr) bv = sRv[d];
            else if (c < 73){
              int idx = e - d + 9;
              if (idx >= 0 && idx <= 18) bv = sHPb[d*HPS + idx];
            } else {
              int ww = e - 119;
              if (d <= ww) bv = sW9[d*12 + ww];
            }
            wi[d] = bv;
          }
          w0=wi[0]; w1=wi[1]; w2=wi[2]; w3=wi[3]; w4=wi[4];
          w5=wi[5]; w6=wi[6]; w7=wi[7]; w8=wi[8]; w9=wi[9];
        }
        float z2l = 0.f;
        for (int j = 0; j < 64; ++j){
          f32x4 lb0 = *(const f32x4*)&sLb[j*LBS];     // rd, L1, L2, L3
          f32x4 lb4 = *(const f32x4*)&sLb[j*LBS + 4]; // L4..L7
          float  l8 = sLb[j*LBS + 8], l9 = sLb[j*LBS + 9];
          float z = w0 * lb0[0];
          zscr[c*ZSS + j] = z;
          z2l += z*z;
          w0 = w1 - lb0[1]*z; w1 = w2 - lb0[2]*z; w2 = w3 - lb0[3]*z;
          w3 = w4 - lb4[0]*z; w4 = w5 - lb4[1]*z; w5 = w6 - lb4[2]*z;
          w6 = w7 - lb4[3]*z; w7 = w8 - l8*z;     w8 = w9 - l9*z;
          int jn = j + 10;
          float bv = 0.f;
          if (isr){ if (jn < 64) bv = sRv[jn]; }
          else if (c < 73){
            if (jn < 64 && j >= e - 19 && j <= e - 1) bv = sHPb[jn*HPS + (e - j - 1)];
          }
          w9 = bv;
        }
        if (isr) sSc[0] = z2l;
        float x1=0.f,x2=0.f,x3=0.f,x4=0.f,x5=0.f,x6=0.f,x7=0.f,x8=0.f,x9=0.f;
        float macc = 0.f, xodd = 0.f;
        for (int j = 63; j >= 0; --j){
          f32x4 lb0 = *(const f32x4*)&sLb[j*LBS];
          f32x4 lb4 = *(const f32x4*)&sLb[j*LBS + 4];
          float  l8 = sLb[j*LBS + 8], l9 = sLb[j*LBS + 9];
          float acc = zscr[c*ZSS + j]
            - lb0[1]*x1 - lb0[2]*x2 - lb0[3]*x3
            - lb4[0]*x4 - lb4[1]*x5 - lb4[2]*x6 - lb4[3]*x7
            - l8*x8 - l9*x9;
          float xj = acc * lb0[0];
          if (!isr){
            macc += sRv[j]*xj;
            if (j & 1) xodd = xj;
            else *(unsigned int*)&KT[e*KTS + j] = pk2bf(xj, xodd);
          }
          x9=x8; x8=x7; x7=x6; x6=x5; x5=x4; x4=x3; x3=x2; x2=x1; x1=xj;
        }
        if (!isr) out_means[((size_t)t*BC + b)*DXC + e] = sXm[e] + macc;
      } else if (c < 129){
        int e = c - 10;                               // 73..118: K columns are zero
        out_means[((size_t)t*BC + b)*DXC + e] = sXm[e];
      }
    }
    __syncthreads();

    // ============ P10: ll ; update xreg += innov @ K ; rewrite Xbf ============
    if (tid == 0){
      llsum += -0.5f*sSc[0] - ldet_t - 58.812066f;    // 0.5*DY*log(2*pi)
    }
    {
      f32x4 uacc[7];
      #pragma unroll
      for (int m = 0; m < 7; ++m) uacc[m] = z4;
      if (wid != 5 && wid != 6){
        const unsigned short* KT = (const unsigned short*)sA;
        #pragma unroll
        for (int kt = 0; kt < 2; ++kt){
          s16x8 bf = *(const s16x8*)&KT[colN*KTS + kt*32 + 8*l4];
          #pragma unroll
          for (int m = 0; m < 7; ++m){
            s16x8 af = *(const s16x8*)&sB[(m*16 + l15)*IVS + kt*32 + 8*l4];
            uacc[m] = mfma16(af, bf, uacc[m]);
          }
        }
      }
      bool upd = ((colN <= 72) || (colN >= 119)) && (wid != 5) && (wid != 6);
      #pragma unroll
      for (int m = 0; m < 7; ++m)
        #pragma unroll
        for (int i = 0; i < 4; ++i){
          int row = m*16 + 4*l4 + i;
          if (row < NMCC){
            float xn = xreg[m][i] + (upd ? uacc[m][i] : 0.f);
            xreg[m][i] = xn;
            sU[row*XBS + colN] = f2bf(xn);
          }
        }
    }
    __syncthreads();
  } // t loop

  if (tid == 0) llp[b] = llsum;
}

// ---------------- final: elbo = -mean(kl) + sum_t mean_b ll ----------------
__global__ void final_kernel(const float* __restrict__ klp, const float* __restrict__ llp,
                             float* __restrict__ out){
  __shared__ float s1[128], s2[128];
  int tid = threadIdx.x;
  s1[tid] = klp[tid];
  s2[tid] = llp[tid];
  __syncthreads();
  if (tid == 0){
    float a = 0.f, c = 0.f;
    for (int i = 0; i < 128; ++i){ a += s1[i]; c += s2[i]; }
    out[0] = -a/128.f + c/128.f;
  }
}

extern "C" void kernel_launch(void* const* d_in, const int* in_sizes, int n_in,
                              void* d_out, int out_size, void* d_ws, size_t ws_size,
                              hipStream_t stream){
  (void)in_sizes; (void)n_in; (void)out_size; (void)ws_size;
  const float* obs  = (const float*)d_in[0];
  const float* W1   = (const float*)d_in[1];
  const float* b1   = (const float*)d_in[2];
  const float* W2   = (const float*)d_in[3];
  const float* b2   = (const float*)d_in[4];
  const float* W3   = (const float*)d_in[5];
  const float* b3   = (const float*)d_in[6];
  const float* W4   = (const float*)d_in[7];
  const float* b4   = (const float*)d_in[8];
  const float* Wih  = (const float*)d_in[9];
  const float* Whh  = (const float*)d_in[10];
  const float* bih  = (const float*)d_in[11];
  const float* Wm   = (const float*)d_in[12];
  const float* bm   = (const float*)d_in[13];
  const float* Wv   = (const float*)d_in[14];
  const float* bv   = (const float*)d_in[15];
  const float* eps0 = (const float*)d_in[16];
  const float* epss = (const float*)d_in[17];
  const float* nsy  = (const float*)d_in[18];

  char* ws = (char*)d_ws;
  float* gin   = (float*)(ws + 0);           // 50*128*256*4 = 6,553,600 B
  float* qmean = (float*)(ws + 6553600);
  float* qstd  = (float*)(ws + 6619136);
  float* klp   = (float*)(ws + 6684672);
  float* llp   = (float*)(ws + 6685184);

  float* out = (float*)d_out;

  hipLaunchKernelGGL(gin_kernel, dim3(TC*BC), dim3(256), 0, stream,
                     obs, Wih, bih, gin);
  hipLaunchKernelGGL(lstm_kernel, dim3(BC), dim3(256), 0, stream,
                     gin, Whh, Wm, bm, Wv, bv, qmean, qstd, klp);
  hipLaunchKernelGGL(enkf_kernel, dim3(BC), dim3(512), 0, stream,
                     obs, W1, b1, W2, b2, W3, b3, W4, b4,
                     eps0, epss, nsy, qmean, qstd, out + 1, llp);
  hipLaunchKernelGGL(final_kernel, dim3(1), dim3(128), 0, stream, klp, llp, out);
}